// Round 1
// baseline (11640.274 us; speedup 1.0000x reference)
//
#include <hip/hip_runtime.h>
#include <hip/hip_bf16.h>
#include <math.h>

// Sizes fixed by the problem
#define BB 32
#define TT 128
#define KK 256
#define HH 512
#define VV 10000
#define VP 10240
#define BT 4096           // B*T
#define G4H 2048          // 4*H
#define HLOG2PI 0.91893853320467274178f

// ---- workspace layout (float offsets) ----
// z       : 0          1048576   (BT*K)
// qz      : 1048576    4096
// h_all   : 1052672    2097152   (BT*H)
// c_ws    : 3149824    16384     (B*H)
// gx      : 3166208    4096
// part    : 3170304    24576     (6*4096)
// region  : 3194880    13117440  (xp overlaid by P,Q,G,cv)
//   xp = region (8388608 = BT*4H)
//   P  = region + 0        (512*10240)   [written AFTER lstm steps]
//   Q  = region + 5242880  (512*10240)
//   G  = region + 10485760 (256*10240)
//   cv = region + 13107200 (10240)
// total 16,312,320 floats = 65.25 MB

__device__ __forceinline__ float softplus_b(float x) {
    // log2(1 + 2^x), stable
    float ax = fabsf(x);
    return fmaxf(x, 0.0f) + log2f(1.0f + exp2f(-ax));
}
__device__ __forceinline__ float sigm(float x) { return 1.0f / (1.0f + expf(-x)); }
__device__ __forceinline__ float f4c(const float4& v, int kk) {
    return kk == 0 ? v.x : kk == 1 ? v.y : kk == 2 ? v.z : v.w;
}
__device__ __forceinline__ void lse_upd8(float& m, float& s, const float* u) {
    float lm = u[0];
#pragma unroll
    for (int j = 1; j < 8; j++) lm = fmaxf(lm, u[j]);
    if (lm > m) { s *= __expf(m - lm); m = lm; }
    float a = 0.f;
#pragma unroll
    for (int j = 0; j < 8; j++) a += __expf(u[j] - m);
    s += a;
}
__device__ __forceinline__ void lse_red(float& m, float& s, int off) {
    float mo = __shfl_xor(m, off);
    float so = __shfl_xor(s, off);
    float mn = fmaxf(m, mo);
    s = s * __expf(m - mn) + so * __expf(mo - mn);
    m = mn;
}

// ---------------- 1) embedding -> z, q_z_lp ----------------
__global__ void k_embed(const int* __restrict__ x, const int* __restrict__ x_sl,
                        const float* __restrict__ eps, const float* __restrict__ emb,
                        float* __restrict__ z, float* __restrict__ qz) {
    int bt = blockIdx.x;
    int b = bt >> 7, t = bt & 127;
    int k = threadIdx.x;
    int xi = x[bt];
    float e1 = emb[xi * 512 + k];
    float sg = softplus_b(emb[xi * 512 + 256 + k]);
    float ep = eps[bt * 256 + k];
    float mk = (t < x_sl[b]) ? 1.f : 0.f;
    z[bt * 256 + k] = (e1 + sg * ep) * mk;
    float q = -HLOG2PI - logf(sg) - 0.5f * ep * ep;
    __shared__ float red[256];
    red[k] = q;
    __syncthreads();
    for (int s = 128; s > 0; s >>= 1) {
        if (k < s) red[k] += red[k + s];
        __syncthreads();
    }
    if (k == 0) qz[bt] = red[0];
}

// ---------------- 2) x_proj = z_shift @ w_ih^T + b_ih + b_hh ----------------
__global__ __launch_bounds__(256) void k_xp(const float* __restrict__ z,
                                            const float* __restrict__ w_ih,
                                            const float* __restrict__ b_ih,
                                            const float* __restrict__ b_hh,
                                            float* __restrict__ xp) {
    __shared__ float At[64][68];
    __shared__ float Wt[64][68];
    int n0 = blockIdx.x * 64, m0 = blockIdx.y * 64;
    int tid = threadIdx.x;
    int tn = tid & 15, tm = tid >> 4;
    float acc[4][4] = {};
    for (int kc = 0; kc < 256; kc += 64) {
        __syncthreads();
        for (int i = tid; i < 1024; i += 256) {
            int r = i >> 4, c4 = i & 15;
            int bt = m0 + r;
            int t = bt & 127;
            float4 v = make_float4(0.f, 0.f, 0.f, 0.f);
            if (t > 0) v = *(const float4*)(z + (bt - 1) * 256 + kc + c4 * 4);
            *(float4*)&At[r][c4 * 4] = v;
        }
        for (int i = tid; i < 1024; i += 256) {
            int r = i >> 4, c4 = i & 15;
            float4 v = *(const float4*)(w_ih + (n0 + r) * 256 + kc + c4 * 4);
            *(float4*)&Wt[r][c4 * 4] = v;
        }
        __syncthreads();
        for (int kk = 0; kk < 16; kk++) {
            float4 a[4], w[4];
#pragma unroll
            for (int i = 0; i < 4; i++) a[i] = *(const float4*)&At[tm + 16 * i][kk * 4];
#pragma unroll
            for (int j = 0; j < 4; j++) w[j] = *(const float4*)&Wt[tn + 16 * j][kk * 4];
#pragma unroll
            for (int i = 0; i < 4; i++)
#pragma unroll
                for (int j = 0; j < 4; j++)
                    acc[i][j] += a[i].x * w[j].x + a[i].y * w[j].y + a[i].z * w[j].z + a[i].w * w[j].w;
        }
    }
#pragma unroll
    for (int i = 0; i < 4; i++) {
        int m = m0 + tm + 16 * i;
#pragma unroll
        for (int j = 0; j < 4; j++) {
            int n = n0 + tn + 16 * j;
            xp[m * 2048 + n] = acc[i][j] + b_ih[n] + b_hh[n];
        }
    }
}

// ---------------- 3) one LSTM step ----------------
__global__ __launch_bounds__(256) void k_step(const float* __restrict__ xp,
                                              const float* __restrict__ w_hh,
                                              float* __restrict__ h_all,
                                              float* __restrict__ c_ws, int t) {
    __shared__ float hl[32 * 512];  // XOR-swizzled by f4 chunk: col (c4 ^ (row&7))
    int g = blockIdx.x;  // 0..63, owns h-cols [g*8, g*8+8)
    int tid = threadIdx.x;
    // stage h_prev (zeros at t==0)
    for (int i = tid; i < 4096; i += 256) {
        int r = i >> 7, c4 = i & 127;
        float4 v = make_float4(0.f, 0.f, 0.f, 0.f);
        if (t > 0) v = *(const float4*)(h_all + ((r << 7) + (t - 1)) * 512 + c4 * 4);
        *(float4*)(hl + r * 512 + ((c4 ^ (r & 7)) << 2)) = v;
    }
    __syncthreads();
    int b = tid >> 3, jj = tid & 7;
    int j = g * 8 + jj;
    float d0 = 0.f, d1 = 0.f, d2 = 0.f, d3 = 0.f;
    if (t > 0) {
        const float* w0 = w_hh + (size_t)(0 * 512 + j) * 512;
        const float* w1 = w_hh + (size_t)(1 * 512 + j) * 512;
        const float* w2 = w_hh + (size_t)(2 * 512 + j) * 512;
        const float* w3 = w_hh + (size_t)(3 * 512 + j) * 512;
        const float* hr = hl + b * 512;
        int sw = b & 7;
#pragma unroll 4
        for (int k4 = 0; k4 < 128; k4++) {
            float4 h4 = *(const float4*)(hr + ((k4 ^ sw) << 2));
            float4 a0 = *(const float4*)(w0 + (k4 << 2));
            float4 a1 = *(const float4*)(w1 + (k4 << 2));
            float4 a2 = *(const float4*)(w2 + (k4 << 2));
            float4 a3 = *(const float4*)(w3 + (k4 << 2));
            d0 += h4.x * a0.x + h4.y * a0.y + h4.z * a0.z + h4.w * a0.w;
            d1 += h4.x * a1.x + h4.y * a1.y + h4.z * a1.z + h4.w * a1.w;
            d2 += h4.x * a2.x + h4.y * a2.y + h4.z * a2.z + h4.w * a2.w;
            d3 += h4.x * a3.x + h4.y * a3.y + h4.z * a3.z + h4.w * a3.w;
        }
    }
    int bt = (b << 7) + t;
    float gi = d0 + xp[bt * 2048 + j];
    float gf = d1 + xp[bt * 2048 + 512 + j];
    float gg = d2 + xp[bt * 2048 + 1024 + j];
    float go = d3 + xp[bt * 2048 + 1536 + j];
    float cp = (t > 0) ? c_ws[b * 512 + j] : 0.f;
    float c = sigm(gf) * cp + sigm(gi) * tanhf(gg);
    float h = sigm(go) * tanhf(c);
    c_ws[b * 512 + j] = c;
    h_all[bt * 512 + j] = h;
}

// ---------------- 4) prior Q ([a; -inv2var]^T) + const_v ----------------
__global__ void k_qconst(const float* __restrict__ emb, float* __restrict__ Q,
                         float* __restrict__ cv) {
    int v = blockIdx.x, k = threadIdx.x;
    float mu = emb[v * 512 + k];
    float sg = softplus_b(emb[v * 512 + 256 + k]);
    float iv = 0.5f / (sg * sg);
    Q[(size_t)k * VP + v] = 2.f * iv * mu;
    Q[(size_t)(256 + k) * VP + v] = -iv;
    float ct = -HLOG2PI - logf(sg) - mu * mu * iv;
    __shared__ float red[256];
    red[k] = ct;
    __syncthreads();
    for (int s = 128; s > 0; s >>= 1) {
        if (k < s) red[k] += red[k + s];
        __syncthreads();
    }
    if (k == 0) cv[v] = red[0];
}

// ---------------- 5) transpose (V x C) -> (C x VP) ----------------
__global__ void k_transpose(const float* __restrict__ in, float* __restrict__ out, int C) {
    __shared__ float tl[32][33];
    int v0 = blockIdx.x * 32, c0 = blockIdx.y * 32;
    int tx = threadIdx.x, ty = threadIdx.y;
#pragma unroll
    for (int i = 0; i < 4; i++) {
        int r = ty + 8 * i;
        int v = v0 + r;
        tl[r][tx] = (v < VV) ? in[(size_t)v * C + c0 + tx] : 0.f;
    }
    __syncthreads();
#pragma unroll
    for (int i = 0; i < 4; i++) {
        int r = ty + 8 * i;
        out[(size_t)(c0 + r) * VP + v0 + tx] = tl[tx][r];
    }
}

// ---------------- 6) fused scores: 3 online logsumexps over V ----------------
__device__ __forceinline__ void dot_phase(const float* __restrict__ f0,
                                          const float* __restrict__ f1,
                                          const float* __restrict__ W, int v0, int nk4,
                                          float acc[2][8]) {
    for (int k4 = 0; k4 < nk4; k4++) {
        float4 z0 = *(const float4*)(f0 + k4 * 4);
        float4 z1 = *(const float4*)(f1 + k4 * 4);
#pragma unroll
        for (int kk = 0; kk < 4; kk++) {
            const float* wp = W + (size_t)(k4 * 4 + kk) * VP + v0;
            float4 w0 = *(const float4*)wp;
            float4 w1 = *(const float4*)(wp + 4);
            float a = f4c(z0, kk), bf = f4c(z1, kk);
            acc[0][0] += a * w0.x; acc[0][1] += a * w0.y; acc[0][2] += a * w0.z; acc[0][3] += a * w0.w;
            acc[0][4] += a * w1.x; acc[0][5] += a * w1.y; acc[0][6] += a * w1.z; acc[0][7] += a * w1.w;
            acc[1][0] += bf * w0.x; acc[1][1] += bf * w0.y; acc[1][2] += bf * w0.z; acc[1][3] += bf * w0.w;
            acc[1][4] += bf * w1.x; acc[1][5] += bf * w1.y; acc[1][6] += bf * w1.z; acc[1][7] += bf * w1.w;
        }
    }
}

__global__ __launch_bounds__(512) void k_scores(const float* __restrict__ h_all,
                                                const float* __restrict__ z,
                                                const float* __restrict__ P,
                                                const float* __restrict__ Q,
                                                const float* __restrict__ Gm,
                                                const float* __restrict__ cv,
                                                const float* __restrict__ b_prior,
                                                const float* __restrict__ b_gen,
                                                float* __restrict__ part) {
    __shared__ float hT[16 * 512];
    __shared__ float fz[16 * 512];  // [z(256); z^2(256)] per row
    int tid = threadIdx.x;
    int bt0 = blockIdx.x * 16;
    for (int i = tid; i < 2048; i += 512) {
        int r = i >> 7, c4 = i & 127;
        *(float4*)&hT[r * 512 + c4 * 4] = *(const float4*)(h_all + (bt0 + r) * 512 + c4 * 4);
    }
    for (int i = tid; i < 1024; i += 512) {
        int r = i >> 6, c4 = i & 63;
        float4 v = *(const float4*)(z + (bt0 + r) * 256 + c4 * 4);
        *(float4*)&fz[r * 512 + c4 * 4] = v;
        float4 v2 = make_float4(v.x * v.x, v.y * v.y, v.z * v.z, v.w * v.w);
        *(float4*)&fz[r * 512 + 256 + c4 * 4] = v2;
    }
    __syncthreads();
    int btg = tid >> 6;  // 0..7 == wave id
    int vl = tid & 63;
    const float* h0 = hT + (btg * 2 + 0) * 512;
    const float* h1 = hT + (btg * 2 + 1) * 512;
    const float* z0p = fz + (btg * 2 + 0) * 512;
    const float* z1p = fz + (btg * 2 + 1) * 512;
    float m1[2] = {-1e30f, -1e30f}, s1[2] = {0.f, 0.f};
    float m2[2] = {-1e30f, -1e30f}, s2[2] = {0.f, 0.f};
    float m3[2] = {-1e30f, -1e30f}, s3[2] = {0.f, 0.f};
#pragma unroll 1
    for (int it = 0; it < 20; it++) {
        int v0 = it * 512 + vl * 8;
        // phase C: gen logits, K=256 (first half of fz rows)
        {
            float accC[2][8] = {};
            dot_phase(z0p, z1p, Gm, v0, 64, accC);
            float u[8];
#pragma unroll
            for (int i = 0; i < 2; i++) {
#pragma unroll
                for (int j = 0; j < 8; j++) {
                    int v = v0 + j;
                    u[j] = (v < VV) ? accC[i][j] + b_gen[v] : -1e30f;
                }
                lse_upd8(m3[i], s3[i], u);
            }
        }
        // phase A: prior logits u, K=512
        float accA[2][8] = {};
        dot_phase(h0, h1, P, v0, 128, accA);
        // phase B: lp body, K=512 on [z; z^2] vs [a; -inv2var]
        float accB[2][8] = {};
        dot_phase(z0p, z1p, Q, v0, 128, accB);
        float u[8];
#pragma unroll
        for (int i = 0; i < 2; i++) {
#pragma unroll
            for (int j = 0; j < 8; j++) {
                int v = v0 + j;
                u[j] = (v < VV) ? accA[i][j] + b_prior[v] : -1e30f;
            }
            lse_upd8(m1[i], s1[i], u);
#pragma unroll
            for (int j = 0; j < 8; j++) {
                int v = v0 + j;
                u[j] = (v < VV) ? u[j] + accB[i][j] + cv[v] : -1e30f;
            }
            lse_upd8(m2[i], s2[i], u);
        }
    }
    // reduce across the 64 lanes of this wave (same 2 bt rows)
#pragma unroll
    for (int off = 1; off < 64; off <<= 1) {
#pragma unroll
        for (int i = 0; i < 2; i++) {
            lse_red(m1[i], s1[i], off);
            lse_red(m2[i], s2[i], off);
            lse_red(m3[i], s3[i], off);
        }
    }
    if (vl == 0) {
#pragma unroll
        for (int i = 0; i < 2; i++) {
            int bt = bt0 + btg * 2 + i;
            part[0 * 4096 + bt] = m1[i];
            part[1 * 4096 + bt] = s1[i];
            part[2 * 4096 + bt] = m2[i];
            part[3 * 4096 + bt] = s2[i];
            part[4 * 4096 + bt] = m3[i];
            part[5 * 4096 + bt] = s3[i];
        }
    }
}

// ---------------- 7) gx = z . w_gen[x] + b_gen[x] ----------------
__global__ void k_gx(const float* __restrict__ z, const int* __restrict__ x,
                     const float* __restrict__ w_gen, const float* __restrict__ b_gen,
                     float* __restrict__ gx) {
    int bt = blockIdx.x, k = threadIdx.x;
    int xi = x[bt];
    float p = z[bt * 256 + k] * w_gen[xi * 256 + k];
    __shared__ float red[256];
    red[k] = p;
    __syncthreads();
    for (int s = 128; s > 0; s >>= 1) {
        if (k < s) red[k] += red[k + s];
        __syncthreads();
    }
    if (k == 0) gx[bt] = red[0] + b_gen[xi];
}

// ---------------- 8) finalize ----------------
__global__ void k_final(const float* __restrict__ part, const float* __restrict__ qz,
                        const float* __restrict__ gxv, const int* __restrict__ x_sl,
                        float* __restrict__ out) {
    int tid = threadIdx.x;
    float S = 0.f;
    for (int bt = tid; bt < 4096; bt += 256) {
        int b = bt >> 7, t = bt & 127;
        if (t < x_sl[b]) {
            float lse1 = part[0 * 4096 + bt] + logf(part[1 * 4096 + bt]);
            float lse2 = part[2 * 4096 + bt] + logf(part[3 * 4096 + bt]);
            float lse3 = part[4 * 4096 + bt] + logf(part[5 * 4096 + bt]);
            float p_z = lse2 - lse1;
            float kl = qz[bt] - p_z;
            float px = gxv[bt] - lse3;
            S += px - kl;
        }
    }
    __shared__ float red[256];
    red[tid] = S;
    __syncthreads();
    for (int s = 128; s > 0; s >>= 1) {
        if (tid < s) red[tid] += red[tid + s];
        __syncthreads();
    }
    if (tid == 0) {
        int sl = 0;
        for (int b = 0; b < 32; b++) sl += x_sl[b];
        out[0] = -(red[0] / (float)sl);
    }
}

extern "C" void kernel_launch(void* const* d_in, const int* in_sizes, int n_in,
                              void* d_out, int out_size, void* d_ws, size_t ws_size,
                              hipStream_t stream) {
    const int* x = (const int*)d_in[0];
    const int* x_sl = (const int*)d_in[1];
    const float* eps = (const float*)d_in[2];
    const float* emb = (const float*)d_in[3];
    const float* w_ih = (const float*)d_in[4];
    const float* w_hh = (const float*)d_in[5];
    const float* b_ih = (const float*)d_in[6];
    const float* b_hh = (const float*)d_in[7];
    const float* w_prior = (const float*)d_in[8];
    const float* b_prior = (const float*)d_in[9];
    const float* w_gen = (const float*)d_in[10];
    const float* b_gen = (const float*)d_in[11];

    float* ws = (float*)d_ws;
    float* z = ws;
    float* qz = ws + 1048576;
    float* h_all = ws + 1052672;
    float* c_ws = ws + 3149824;
    float* gx = ws + 3166208;
    float* part = ws + 3170304;
    float* region = ws + 3194880;
    float* xp = region;
    float* P = region;
    float* Q = region + 5242880;
    float* G = region + 10485760;
    float* cv = region + 13107200;

    k_embed<<<4096, 256, 0, stream>>>(x, x_sl, eps, emb, z, qz);
    k_xp<<<dim3(32, 64), 256, 0, stream>>>(z, w_ih, b_ih, b_hh, xp);
    for (int t = 0; t < 128; t++)
        k_step<<<64, 256, 0, stream>>>(xp, w_hh, h_all, c_ws, t);
    // xp is dead now; overlay P/Q/G/cv on the same region
    k_qconst<<<10000, 256, 0, stream>>>(emb, Q, cv);
    k_transpose<<<dim3(313, 16), dim3(32, 8), 0, stream>>>(w_prior, P, 512);
    k_transpose<<<dim3(313, 8), dim3(32, 8), 0, stream>>>(w_gen, G, 256);
    k_scores<<<256, 512, 0, stream>>>(h_all, z, P, Q, G, cv, b_prior, b_gen, part);
    k_gx<<<4096, 256, 0, stream>>>(z, x, w_gen, b_gen, gx);
    k_final<<<1, 256, 0, stream>>>(part, qz, gx, x_sl, (float*)d_out);
}

// Round 2
// 10993.977 us; speedup vs baseline: 1.0588x; 1.0588x over previous
//
#include <hip/hip_runtime.h>
#include <hip/hip_bf16.h>
#include <hip/hip_cooperative_groups.h>
#include <math.h>

namespace cg = cooperative_groups;

// Sizes fixed by the problem
#define BB 32
#define TT 128
#define KK 256
#define HH 512
#define VV 10000
#define VP 10240
#define BT 4096           // B*T
#define HLOG2PI 0.91893853320467274178f

// ---- workspace layout (float offsets) ----
// z       : 0          1048576   (BT*K)
// qz      : 1048576    4096
// h_all   : 1052672    2097152   (BT*H)
// gx      : 3149824    4096
// part    : 3153920    98304     (4 vs * 6 * 4096)
// region  : 3252224    13117440  (xp overlaid by P,Q,G,cv)
//   xp = region (8388608 = BT*4H)   [dead after k_lstm]
//   P  = region + 0        (512*10240)
//   Q  = region + 5242880  (512*10240)
//   G  = region + 10485760 (256*10240)
//   cv = region + 13107200 (10240)
// total 16,369,664 floats = 65.5 MB

__device__ __forceinline__ float softplus_b(float x) {
    float ax = fabsf(x);
    return fmaxf(x, 0.0f) + log2f(1.0f + exp2f(-ax));
}
__device__ __forceinline__ float sigm(float x) { return 1.0f / (1.0f + expf(-x)); }
__device__ __forceinline__ float bf2f(unsigned short u) {
    return __uint_as_float(((unsigned)u) << 16);
}
__device__ __forceinline__ unsigned short f2bf(float f) {
    unsigned u = __float_as_uint(f);
    u += 0x7FFFu + ((u >> 16) & 1u);
    return (unsigned short)(u >> 16);
}
__device__ __forceinline__ void lse_upd8(float& m, float& s, const float* u) {
    float lm = u[0];
#pragma unroll
    for (int j = 1; j < 8; j++) lm = fmaxf(lm, u[j]);
    if (lm > m) { s *= __expf(m - lm); m = lm; }
    float a = 0.f;
#pragma unroll
    for (int j = 0; j < 8; j++) a += __expf(u[j] - m);
    s += a;
}
__device__ __forceinline__ void lse_red(float& m, float& s, int off) {
    float mo = __shfl_xor(m, off);
    float so = __shfl_xor(s, off);
    float mn = fmaxf(m, mo);
    s = s * __expf(m - mn) + so * __expf(mo - mn);
    m = mn;
}

// ---------------- 1) embedding -> z, q_z_lp ----------------
__global__ void k_embed(const int* __restrict__ x, const int* __restrict__ x_sl,
                        const float* __restrict__ eps, const float* __restrict__ emb,
                        float* __restrict__ z, float* __restrict__ qz) {
    int bt = blockIdx.x;
    int b = bt >> 7, t = bt & 127;
    int k = threadIdx.x;
    int xi = x[bt];
    float e1 = emb[xi * 512 + k];
    float sg = softplus_b(emb[xi * 512 + 256 + k]);
    float ep = eps[bt * 256 + k];
    float mk = (t < x_sl[b]) ? 1.f : 0.f;
    z[bt * 256 + k] = (e1 + sg * ep) * mk;
    float q = -HLOG2PI - logf(sg) - 0.5f * ep * ep;
    __shared__ float red[256];
    red[k] = q;
    __syncthreads();
    for (int s = 128; s > 0; s >>= 1) {
        if (k < s) red[k] += red[k + s];
        __syncthreads();
    }
    if (k == 0) qz[bt] = red[0];
}

// ---------------- 2) x_proj = z_shift @ w_ih^T + b_ih + b_hh ----------------
__global__ __launch_bounds__(256) void k_xp(const float* __restrict__ z,
                                            const float* __restrict__ w_ih,
                                            const float* __restrict__ b_ih,
                                            const float* __restrict__ b_hh,
                                            float* __restrict__ xp) {
    __shared__ float At[64][68];
    __shared__ float Wt[64][68];
    int n0 = blockIdx.x * 64, m0 = blockIdx.y * 64;
    int tid = threadIdx.x;
    int tn = tid & 15, tm = tid >> 4;
    float acc[4][4] = {};
    for (int kc = 0; kc < 256; kc += 64) {
        __syncthreads();
        for (int i = tid; i < 1024; i += 256) {
            int r = i >> 4, c4 = i & 15;
            int bt = m0 + r;
            int t = bt & 127;
            float4 v = make_float4(0.f, 0.f, 0.f, 0.f);
            if (t > 0) v = *(const float4*)(z + (bt - 1) * 256 + kc + c4 * 4);
            *(float4*)&At[r][c4 * 4] = v;
        }
        for (int i = tid; i < 1024; i += 256) {
            int r = i >> 4, c4 = i & 15;
            float4 v = *(const float4*)(w_ih + (n0 + r) * 256 + kc + c4 * 4);
            *(float4*)&Wt[r][c4 * 4] = v;
        }
        __syncthreads();
        for (int kk = 0; kk < 16; kk++) {
            float4 a[4], w[4];
#pragma unroll
            for (int i = 0; i < 4; i++) a[i] = *(const float4*)&At[tm + 16 * i][kk * 4];
#pragma unroll
            for (int j = 0; j < 4; j++) w[j] = *(const float4*)&Wt[tn + 16 * j][kk * 4];
#pragma unroll
            for (int i = 0; i < 4; i++)
#pragma unroll
                for (int j = 0; j < 4; j++)
                    acc[i][j] += a[i].x * w[j].x + a[i].y * w[j].y + a[i].z * w[j].z + a[i].w * w[j].w;
        }
    }
#pragma unroll
    for (int i = 0; i < 4; i++) {
        int m = m0 + tm + 16 * i;
#pragma unroll
        for (int j = 0; j < 4; j++) {
            int n = n0 + tn + 16 * j;
            xp[m * 2048 + n] = acc[i][j] + b_ih[n] + b_hh[n];
        }
    }
}

// ---------------- 3) full LSTM recurrence, one cooperative kernel ----------------
// 256 blocks x 64 threads. Block g owns j in {2g, 2g+1}; thread (b, rg) computes
// all 4 gates for (b, j=2g+rg). w_hh rows (16 KB/block) stay L1-hot; h_prev is
// staged to LDS (XOR swizzle breaks the 512-stride bank collision); c in regs.
__global__ __launch_bounds__(64) void k_lstm(const float* __restrict__ xp,
                                             const float* __restrict__ w_hh,
                                             float* __restrict__ h_all) {
    cg::grid_group grid = cg::this_grid();
    __shared__ float hl[32 * 512];
    int g = blockIdx.x;
    int tid = threadIdx.x;
    int b = tid & 31;
    int rg = tid >> 5;
    int j = (g << 1) + rg;
    const float* w0 = w_hh + (size_t)j * 512;
    const float* w1 = w_hh + (size_t)(512 + j) * 512;
    const float* w2 = w_hh + (size_t)(1024 + j) * 512;
    const float* w3 = w_hh + (size_t)(1536 + j) * 512;
    const float* hr = hl + b * 512;
    int sw = b & 7;
    float c = 0.f;
    for (int t = 0; t < 128; t++) {
        float d0 = 0.f, d1 = 0.f, d2 = 0.f, d3 = 0.f;
        if (t > 0) {
            for (int i = tid; i < 4096; i += 64) {
                int r = i >> 7, c4 = i & 127;
                float4 v = *(const float4*)(h_all + (size_t)((r << 7) + t - 1) * 512 + (c4 << 2));
                *(float4*)(hl + r * 512 + ((c4 ^ (r & 7)) << 2)) = v;
            }
            __syncthreads();
#pragma unroll 2
            for (int k4 = 0; k4 < 128; k4++) {
                float4 h4 = *(const float4*)(hr + ((k4 ^ sw) << 2));
                float4 a0 = *(const float4*)(w0 + (k4 << 2));
                float4 a1 = *(const float4*)(w1 + (k4 << 2));
                float4 a2 = *(const float4*)(w2 + (k4 << 2));
                float4 a3 = *(const float4*)(w3 + (k4 << 2));
                d0 += h4.x * a0.x + h4.y * a0.y + h4.z * a0.z + h4.w * a0.w;
                d1 += h4.x * a1.x + h4.y * a1.y + h4.z * a1.z + h4.w * a1.w;
                d2 += h4.x * a2.x + h4.y * a2.y + h4.z * a2.z + h4.w * a2.w;
                d3 += h4.x * a3.x + h4.y * a3.y + h4.z * a3.z + h4.w * a3.w;
            }
        }
        int bt = (b << 7) + t;
        const float* xpr = xp + (size_t)bt * 2048 + j;
        float gi = d0 + xpr[0];
        float gf = d1 + xpr[512];
        float gg = d2 + xpr[1024];
        float go = d3 + xpr[1536];
        c = sigm(gf) * c + sigm(gi) * tanhf(gg);
        float h = sigm(go) * tanhf(c);
        h_all[(size_t)bt * 512 + j] = h;
        __threadfence();
        grid.sync();
    }
}

// ---------------- 4) prior Q ([a; -inv2var]^T) + const_v ----------------
__global__ void k_qconst(const float* __restrict__ emb, float* __restrict__ Q,
                         float* __restrict__ cv) {
    int v = blockIdx.x, k = threadIdx.x;
    float mu = emb[v * 512 + k];
    float sg = softplus_b(emb[v * 512 + 256 + k]);
    float iv = 0.5f / (sg * sg);
    Q[(size_t)k * VP + v] = 2.f * iv * mu;
    Q[(size_t)(256 + k) * VP + v] = -iv;
    float ct = -HLOG2PI - logf(sg) - mu * mu * iv;
    __shared__ float red[256];
    red[k] = ct;
    __syncthreads();
    for (int s = 128; s > 0; s >>= 1) {
        if (k < s) red[k] += red[k + s];
        __syncthreads();
    }
    if (k == 0) cv[v] = red[0];
}

// ---------------- 5) transpose (V x C) -> (C x VP) ----------------
__global__ void k_transpose(const float* __restrict__ in, float* __restrict__ out, int C) {
    __shared__ float tl[32][33];
    int v0 = blockIdx.x * 32, c0 = blockIdx.y * 32;
    int tx = threadIdx.x, ty = threadIdx.y;
#pragma unroll
    for (int i = 0; i < 4; i++) {
        int r = ty + 8 * i;
        int v = v0 + r;
        tl[r][tx] = (v < VV) ? in[(size_t)v * C + c0 + tx] : 0.f;
    }
    __syncthreads();
#pragma unroll
    for (int i = 0; i < 4; i++) {
        int r = ty + 8 * i;
        out[(size_t)(c0 + r) * VP + v0 + tx] = tl[tx][r];
    }
}

// ---------------- 6) fused scores ----------------
// 64 bt rows/block (bf16 staging, 128 KB dyn LDS), 4-way V split -> 256 blocks.
// Weight streams read 64x (was 256x): 3.3 GB total.
__device__ __forceinline__ void dot8(const unsigned short* __restrict__ F,
                                     const float* __restrict__ W, int nk4,
                                     float acc[8][8]) {
    for (int k4 = 0; k4 < nk4; k4++) {
        float zf[8][4];
#pragma unroll
        for (int i = 0; i < 8; i++) {
            ushort4 u = *(const ushort4*)(F + i * 512 + (k4 << 2));
            zf[i][0] = bf2f(u.x); zf[i][1] = bf2f(u.y);
            zf[i][2] = bf2f(u.z); zf[i][3] = bf2f(u.w);
        }
        const float* wk = W + (size_t)(k4 << 2) * VP;
#pragma unroll
        for (int kk = 0; kk < 4; kk++) {
            float4 w0 = *(const float4*)wk;
            float4 w1 = *(const float4*)(wk + 4);
            wk += VP;
#pragma unroll
            for (int i = 0; i < 8; i++) {
                acc[i][0] += zf[i][kk] * w0.x;
                acc[i][1] += zf[i][kk] * w0.y;
                acc[i][2] += zf[i][kk] * w0.z;
                acc[i][3] += zf[i][kk] * w0.w;
                acc[i][4] += zf[i][kk] * w1.x;
                acc[i][5] += zf[i][kk] * w1.y;
                acc[i][6] += zf[i][kk] * w1.z;
                acc[i][7] += zf[i][kk] * w1.w;
            }
        }
    }
}

__global__ __launch_bounds__(512) void k_scores(const float* __restrict__ h_all,
                                                const float* __restrict__ z,
                                                const float* __restrict__ P,
                                                const float* __restrict__ Q,
                                                const float* __restrict__ Gm,
                                                const float* __restrict__ cv,
                                                const float* __restrict__ b_prior,
                                                const float* __restrict__ b_gen,
                                                float* __restrict__ part) {
    extern __shared__ unsigned short sm[];
    unsigned short* hT = sm;             // 64 x 512 bf16
    unsigned short* fz = sm + 64 * 512;  // 64 x [z(256) | z^2(256)] bf16
    int tid = threadIdx.x;
    int bt0 = blockIdx.x * 64;
    int vbase = blockIdx.y * 2560;
    for (int i = tid; i < 8192; i += 512) {
        int r = i >> 7, c4 = i & 127;
        float4 v = *(const float4*)(h_all + (size_t)(bt0 + r) * 512 + (c4 << 2));
        *(ushort4*)(hT + r * 512 + (c4 << 2)) =
            make_ushort4(f2bf(v.x), f2bf(v.y), f2bf(v.z), f2bf(v.w));
    }
    for (int i = tid; i < 4096; i += 512) {
        int r = i >> 6, c4 = i & 63;
        float4 v = *(const float4*)(z + (size_t)(bt0 + r) * 256 + (c4 << 2));
        *(ushort4*)(fz + r * 512 + (c4 << 2)) =
            make_ushort4(f2bf(v.x), f2bf(v.y), f2bf(v.z), f2bf(v.w));
        *(ushort4*)(fz + r * 512 + 256 + (c4 << 2)) =
            make_ushort4(f2bf(v.x * v.x), f2bf(v.y * v.y), f2bf(v.z * v.z), f2bf(v.w * v.w));
    }
    __syncthreads();
    int w = tid >> 6, vl = tid & 63;
    const unsigned short* Fh = hT + (w * 8) * 512;
    const unsigned short* Fz = fz + (w * 8) * 512;
    float m1[8], s1[8], m2[8], s2[8], m3[8], s3[8];
#pragma unroll
    for (int i = 0; i < 8; i++) {
        m1[i] = m2[i] = m3[i] = -1e30f;
        s1[i] = s2[i] = s3[i] = 0.f;
    }
    for (int it = 0; it < 5; it++) {
        int v0 = vbase + it * 512 + vl * 8;
        float bp[8], bg[8], cvv[8];
#pragma unroll
        for (int j = 0; j < 8; j++) {
            int v = v0 + j;
            bool ok = v < VV;
            bp[j] = ok ? b_prior[v] : 0.f;
            bg[j] = ok ? b_gen[v] : 0.f;
            cvv[j] = ok ? cv[v] : 0.f;
        }
        // phase C: gen logits (K=256, z half of fz)
        {
            float acc[8][8] = {};
            dot8(Fz, Gm + v0, 64, acc);
            float u[8];
#pragma unroll
            for (int i = 0; i < 8; i++) {
#pragma unroll
                for (int j = 0; j < 8; j++)
                    u[j] = (v0 + j < VV) ? acc[i][j] + bg[j] : -1e30f;
                lse_upd8(m3[i], s3[i], u);
            }
        }
        // phase A: prior logits (K=512 on h)
        float accA[8][8] = {};
        dot8(Fh, P + v0, 128, accA);
        // phase B: lp body (K=512 on [z; z^2])
        float accB[8][8] = {};
        dot8(Fz, Q + v0, 128, accB);
        float u[8];
#pragma unroll
        for (int i = 0; i < 8; i++) {
#pragma unroll
            for (int j = 0; j < 8; j++)
                u[j] = (v0 + j < VV) ? accA[i][j] + bp[j] : -1e30f;
            lse_upd8(m1[i], s1[i], u);
#pragma unroll
            for (int j = 0; j < 8; j++)
                u[j] = (v0 + j < VV) ? u[j] + accB[i][j] + cvv[j] : -1e30f;
            lse_upd8(m2[i], s2[i], u);
        }
    }
#pragma unroll
    for (int off = 1; off < 64; off <<= 1) {
#pragma unroll
        for (int i = 0; i < 8; i++) {
            lse_red(m1[i], s1[i], off);
            lse_red(m2[i], s2[i], off);
            lse_red(m3[i], s3[i], off);
        }
    }
    if (vl == 0) {
        int base = blockIdx.y * 6;
#pragma unroll
        for (int i = 0; i < 8; i++) {
            int bt = bt0 + w * 8 + i;
            part[(base + 0) * 4096 + bt] = m1[i];
            part[(base + 1) * 4096 + bt] = s1[i];
            part[(base + 2) * 4096 + bt] = m2[i];
            part[(base + 3) * 4096 + bt] = s2[i];
            part[(base + 4) * 4096 + bt] = m3[i];
            part[(base + 5) * 4096 + bt] = s3[i];
        }
    }
}

// ---------------- 7) gx = z . w_gen[x] + b_gen[x] ----------------
__global__ void k_gx(const float* __restrict__ z, const int* __restrict__ x,
                     const float* __restrict__ w_gen, const float* __restrict__ b_gen,
                     float* __restrict__ gx) {
    int bt = blockIdx.x, k = threadIdx.x;
    int xi = x[bt];
    float p = z[bt * 256 + k] * w_gen[xi * 256 + k];
    __shared__ float red[256];
    red[k] = p;
    __syncthreads();
    for (int s = 128; s > 0; s >>= 1) {
        if (k < s) red[k] += red[k + s];
        __syncthreads();
    }
    if (k == 0) gx[bt] = red[0] + b_gen[xi];
}

// ---------------- 8) finalize (merge 4 V-split partials) ----------------
__device__ __forceinline__ float lse4(const float* __restrict__ part, int comp, int bt) {
    float M = -1e30f, S = 0.f;
#pragma unroll
    for (int vs = 0; vs < 4; vs++) {
        float m = part[(vs * 6 + comp) * 4096 + bt];
        float s = part[(vs * 6 + comp + 1) * 4096 + bt];
        float Mn = fmaxf(M, m);
        S = S * __expf(M - Mn) + s * __expf(m - Mn);
        M = Mn;
    }
    return M + logf(S);
}

__global__ void k_final(const float* __restrict__ part, const float* __restrict__ qz,
                        const float* __restrict__ gxv, const int* __restrict__ x_sl,
                        float* __restrict__ out) {
    int tid = threadIdx.x;
    float S = 0.f;
    for (int bt = tid; bt < 4096; bt += 256) {
        int b = bt >> 7, t = bt & 127;
        if (t < x_sl[b]) {
            float lse1 = lse4(part, 0, bt);
            float lse2 = lse4(part, 2, bt);
            float lse3 = lse4(part, 4, bt);
            float p_z = lse2 - lse1;
            float kl = qz[bt] - p_z;
            float px = gxv[bt] - lse3;
            S += px - kl;
        }
    }
    __shared__ float red[256];
    red[tid] = S;
    __syncthreads();
    for (int s = 128; s > 0; s >>= 1) {
        if (tid < s) red[tid] += red[tid + s];
        __syncthreads();
    }
    if (tid == 0) {
        int sl = 0;
        for (int b = 0; b < 32; b++) sl += x_sl[b];
        out[0] = -(red[0] / (float)sl);
    }
}

extern "C" void kernel_launch(void* const* d_in, const int* in_sizes, int n_in,
                              void* d_out, int out_size, void* d_ws, size_t ws_size,
                              hipStream_t stream) {
    const int* x = (const int*)d_in[0];
    const int* x_sl = (const int*)d_in[1];
    const float* eps = (const float*)d_in[2];
    const float* emb = (const float*)d_in[3];
    const float* w_ih = (const float*)d_in[4];
    const float* w_hh = (const float*)d_in[5];
    const float* b_ih = (const float*)d_in[6];
    const float* b_hh = (const float*)d_in[7];
    const float* w_prior = (const float*)d_in[8];
    const float* b_prior = (const float*)d_in[9];
    const float* w_gen = (const float*)d_in[10];
    const float* b_gen = (const float*)d_in[11];

    float* ws = (float*)d_ws;
    float* z = ws;
    float* qz = ws + 1048576;
    float* h_all = ws + 1052672;
    float* gx = ws + 3149824;
    float* part = ws + 3153920;
    float* region = ws + 3252224;
    float* xp = region;
    float* P = region;
    float* Q = region + 5242880;
    float* G = region + 10485760;
    float* cv = region + 13107200;

    k_embed<<<4096, 256, 0, stream>>>(x, x_sl, eps, emb, z, qz);
    k_xp<<<dim3(32, 64), 256, 0, stream>>>(z, w_ih, b_ih, b_hh, xp);
    {
        void* args[] = {(void*)&xp, (void*)&w_hh, (void*)&h_all};
        hipLaunchCooperativeKernel((const void*)k_lstm, dim3(256), dim3(64), args, 0, stream);
    }
    // xp dead; overlay P/Q/G/cv
    k_qconst<<<10000, 256, 0, stream>>>(emb, Q, cv);
    k_transpose<<<dim3(313, 16), dim3(32, 8), 0, stream>>>(w_prior, P, 512);
    k_transpose<<<dim3(313, 8), dim3(32, 8), 0, stream>>>(w_gen, G, 256);
    hipFuncSetAttribute((const void*)k_scores, hipFuncAttributeMaxDynamicSharedMemorySize, 131072);
    k_scores<<<dim3(64, 4), 512, 131072, stream>>>(h_all, z, P, Q, G, cv, b_prior, b_gen, part);
    k_gx<<<4096, 256, 0, stream>>>(z, x, w_gen, b_gen, gx);
    k_final<<<1, 256, 0, stream>>>(part, qz, gx, x_sl, (float*)d_out);
}

// Round 3
// 9589.474 us; speedup vs baseline: 1.2139x; 1.1465x over previous
//
#include <hip/hip_runtime.h>
#include <hip/hip_bf16.h>
#include <hip/hip_cooperative_groups.h>
#include <math.h>

namespace cg = cooperative_groups;

// Sizes fixed by the problem
#define BB 32
#define TT 128
#define KK 256
#define HH 512
#define VV 10000
#define VP 10240
#define BT 4096           // B*T
#define HLOG2PI 0.91893853320467274178f

// ---- workspace layout (float offsets) ----
// z       : 0          1048576   (BT*K)
// qz      : 1048576    4096
// h_all   : 1052672    2097152   (BT*H)
// gx      : 3149824    4096
// part    : 3153920    98304     (4 vs * 6 * 4096)
// region  : 3252224    13117440  (xp overlaid by P,Q,G,cv)
//   xp = region (8388608 = BT*4H)   [dead after k_lstm]
//   P  = region + 0        (512*10240)
//   Q  = region + 5242880  (512*10240)
//   G  = region + 10485760 (256*10240)
//   cv = region + 13107200 (10240)
// total 16,369,664 floats = 65.5 MB

__device__ __forceinline__ float softplus_b(float x) {
    float ax = fabsf(x);
    return fmaxf(x, 0.0f) + log2f(1.0f + exp2f(-ax));
}
__device__ __forceinline__ float sigm(float x) { return 1.0f / (1.0f + expf(-x)); }
__device__ __forceinline__ float bf2f(unsigned short u) {
    return __uint_as_float(((unsigned)u) << 16);
}
__device__ __forceinline__ unsigned short f2bf(float f) {
    unsigned u = __float_as_uint(f);
    u += 0x7FFFu + ((u >> 16) & 1u);
    return (unsigned short)(u >> 16);
}
__device__ __forceinline__ void lse_upd8(float& m, float& s, const float* u) {
    float lm = u[0];
#pragma unroll
    for (int j = 1; j < 8; j++) lm = fmaxf(lm, u[j]);
    if (lm > m) { s *= __expf(m - lm); m = lm; }
    float a = 0.f;
#pragma unroll
    for (int j = 0; j < 8; j++) a += __expf(u[j] - m);
    s += a;
}
__device__ __forceinline__ void lse_red(float& m, float& s, int off) {
    float mo = __shfl_xor(m, off);
    float so = __shfl_xor(s, off);
    float mn = fmaxf(m, mo);
    s = s * __expf(m - mn) + so * __expf(mo - mn);
    m = mn;
}

// ---------------- 1) embedding -> z, q_z_lp ----------------
__global__ void k_embed(const int* __restrict__ x, const int* __restrict__ x_sl,
                        const float* __restrict__ eps, const float* __restrict__ emb,
                        float* __restrict__ z, float* __restrict__ qz) {
    int bt = blockIdx.x;
    int b = bt >> 7, t = bt & 127;
    int k = threadIdx.x;
    int xi = x[bt];
    float e1 = emb[xi * 512 + k];
    float sg = softplus_b(emb[xi * 512 + 256 + k]);
    float ep = eps[bt * 256 + k];
    float mk = (t < x_sl[b]) ? 1.f : 0.f;
    z[bt * 256 + k] = (e1 + sg * ep) * mk;
    float q = -HLOG2PI - logf(sg) - 0.5f * ep * ep;
    __shared__ float red[256];
    red[k] = q;
    __syncthreads();
    for (int s = 128; s > 0; s >>= 1) {
        if (k < s) red[k] += red[k + s];
        __syncthreads();
    }
    if (k == 0) qz[bt] = red[0];
}

// ---------------- 2) x_proj = z_shift @ w_ih^T + b_ih + b_hh ----------------
__global__ __launch_bounds__(256) void k_xp(const float* __restrict__ z,
                                            const float* __restrict__ w_ih,
                                            const float* __restrict__ b_ih,
                                            const float* __restrict__ b_hh,
                                            float* __restrict__ xp) {
    __shared__ float At[64][68];
    __shared__ float Wt[64][68];
    int n0 = blockIdx.x * 64, m0 = blockIdx.y * 64;
    int tid = threadIdx.x;
    int tn = tid & 15, tm = tid >> 4;
    float acc[4][4] = {};
    for (int kc = 0; kc < 256; kc += 64) {
        __syncthreads();
        for (int i = tid; i < 1024; i += 256) {
            int r = i >> 4, c4 = i & 15;
            int bt = m0 + r;
            int t = bt & 127;
            float4 v = make_float4(0.f, 0.f, 0.f, 0.f);
            if (t > 0) v = *(const float4*)(z + (bt - 1) * 256 + kc + c4 * 4);
            *(float4*)&At[r][c4 * 4] = v;
        }
        for (int i = tid; i < 1024; i += 256) {
            int r = i >> 4, c4 = i & 15;
            float4 v = *(const float4*)(w_ih + (n0 + r) * 256 + kc + c4 * 4);
            *(float4*)&Wt[r][c4 * 4] = v;
        }
        __syncthreads();
        for (int kk = 0; kk < 16; kk++) {
            float4 a[4], w[4];
#pragma unroll
            for (int i = 0; i < 4; i++) a[i] = *(const float4*)&At[tm + 16 * i][kk * 4];
#pragma unroll
            for (int j = 0; j < 4; j++) w[j] = *(const float4*)&Wt[tn + 16 * j][kk * 4];
#pragma unroll
            for (int i = 0; i < 4; i++)
#pragma unroll
                for (int j = 0; j < 4; j++)
                    acc[i][j] += a[i].x * w[j].x + a[i].y * w[j].y + a[i].z * w[j].z + a[i].w * w[j].w;
        }
    }
#pragma unroll
    for (int i = 0; i < 4; i++) {
        int m = m0 + tm + 16 * i;
#pragma unroll
        for (int j = 0; j < 4; j++) {
            int n = n0 + tn + 16 * j;
            xp[m * 2048 + n] = acc[i][j] + b_ih[n] + b_hh[n];
        }
    }
}

// ---------------- 3) full LSTM recurrence, one cooperative kernel ----------------
// 256 blocks x 256 threads, 1 block/CU. Block g owns h-units j in {2g, 2g+1}.
// Weights (8 rows x 512 = 16 KB) are LDS-RESIDENT (read from HBM once).
// Thread = (b, jj, kq): all 4 gate partial-dots over a 128-wide k-quarter,
// reusing each h float4 across the 4 gates. Partials reduced via 4 KB LDS.
// h_prev broadcast through global + grid.sync each step; additive swizzle
// ((k4+r)&127) keeps the 512-stride LDS reads bandwidth-matched.
__global__ __launch_bounds__(256) void k_lstm(const float* __restrict__ xp,
                                              const float* __restrict__ w_hh,
                                              float* __restrict__ h_all) {
    cg::grid_group grid = cg::this_grid();
    extern __shared__ float lds[];
    float* hl = lds;          // 32 x 512 (swizzled)           = 64 KB
    float* wl = lds + 16384;  // 8 rows x 512: row = gate*2+jj = 16 KB
    float* red = lds + 20480; // 4 gates x 4 kq x 64           =  4 KB
    int g = blockIdx.x;
    int tid = threadIdx.x;
    int b = tid & 31;
    int jj = (tid >> 5) & 1;
    int kq = tid >> 6;  // 0..3
    int j = (g << 1) + jj;
    // one-time weight load: 8 rows x 512 floats, coalesced
    for (int i = tid; i < 1024; i += 256) {
        int row = i >> 7, k4 = i & 127;  // row = gate*2 + jx
        int gate = row >> 1, jx = row & 1;
        float4 v = *(const float4*)(w_hh + (size_t)(gate * 512 + (g << 1) + jx) * 512 + (k4 << 2));
        *(float4*)(wl + row * 512 + (k4 << 2)) = v;
    }
    const float* hr = hl + b * 512;
    const float* w0 = wl + (0 + jj) * 512 + (kq << 7);
    const float* w1 = wl + (2 + jj) * 512 + (kq << 7);
    const float* w2 = wl + (4 + jj) * 512 + (kq << 7);
    const float* w3 = wl + (6 + jj) * 512 + (kq << 7);
    float c = 0.f;
    for (int t = 0; t < 128; t++) {
        float xg0 = 0.f, xg1 = 0.f, xg2 = 0.f, xg3 = 0.f;
        if (tid < 64) {  // issue xp loads early; consumed after the dot phase
            const float* xpr = xp + (size_t)((b << 7) + t) * 2048 + j;
            xg0 = xpr[0]; xg1 = xpr[512]; xg2 = xpr[1024]; xg3 = xpr[1536];
        }
        float d0 = 0.f, d1 = 0.f, d2 = 0.f, d3 = 0.f;
        if (t > 0) {
            __syncthreads();  // hl/red from previous iter fully consumed
            for (int i = tid; i < 4096; i += 256) {
                int r = i >> 7, k4 = i & 127;
                float4 v = *(const float4*)(h_all + (size_t)((r << 7) + t - 1) * 512 + (k4 << 2));
                *(float4*)(hl + r * 512 + (((k4 + r) & 127) << 2)) = v;
            }
            __syncthreads();
            int kbase = kq << 5;
#pragma unroll 4
            for (int k4 = 0; k4 < 32; k4++) {
                int kl = kbase + k4;
                float4 h4 = *(const float4*)(hr + (((kl + b) & 127) << 2));
                float4 a0 = *(const float4*)(w0 + (k4 << 2));
                float4 a1 = *(const float4*)(w1 + (k4 << 2));
                float4 a2 = *(const float4*)(w2 + (k4 << 2));
                float4 a3 = *(const float4*)(w3 + (k4 << 2));
                d0 += h4.x * a0.x + h4.y * a0.y + h4.z * a0.z + h4.w * a0.w;
                d1 += h4.x * a1.x + h4.y * a1.y + h4.z * a1.z + h4.w * a1.w;
                d2 += h4.x * a2.x + h4.y * a2.y + h4.z * a2.z + h4.w * a2.w;
                d3 += h4.x * a3.x + h4.y * a3.y + h4.z * a3.z + h4.w * a3.w;
            }
        }
        int lane64 = (jj << 5) + b;
        red[(0 * 4 + kq) * 64 + lane64] = d0;
        red[(1 * 4 + kq) * 64 + lane64] = d1;
        red[(2 * 4 + kq) * 64 + lane64] = d2;
        red[(3 * 4 + kq) * 64 + lane64] = d3;
        __syncthreads();
        if (tid < 64) {  // tid<64 <=> kq==0, same (b,jj) mapping; c lives here
            float gi = xg0, gf = xg1, gg = xg2, go = xg3;
#pragma unroll
            for (int q = 0; q < 4; q++) {
                gi += red[(0 * 4 + q) * 64 + tid];
                gf += red[(1 * 4 + q) * 64 + tid];
                gg += red[(2 * 4 + q) * 64 + tid];
                go += red[(3 * 4 + q) * 64 + tid];
            }
            c = sigm(gf) * c + sigm(gi) * tanhf(gg);
            float h = sigm(go) * tanhf(c);
            h_all[(size_t)((b << 7) + t) * 512 + j] = h;
        }
        __threadfence();
        grid.sync();
    }
}

// ---------------- 4) prior Q ([a; -inv2var]^T) + const_v ----------------
__global__ void k_qconst(const float* __restrict__ emb, float* __restrict__ Q,
                         float* __restrict__ cv) {
    int v = blockIdx.x, k = threadIdx.x;
    float mu = emb[v * 512 + k];
    float sg = softplus_b(emb[v * 512 + 256 + k]);
    float iv = 0.5f / (sg * sg);
    Q[(size_t)k * VP + v] = 2.f * iv * mu;
    Q[(size_t)(256 + k) * VP + v] = -iv;
    float ct = -HLOG2PI - logf(sg) - mu * mu * iv;
    __shared__ float red[256];
    red[k] = ct;
    __syncthreads();
    for (int s = 128; s > 0; s >>= 1) {
        if (k < s) red[k] += red[k + s];
        __syncthreads();
    }
    if (k == 0) cv[v] = red[0];
}

// ---------------- 5) transpose (V x C) -> (C x VP) ----------------
__global__ void k_transpose(const float* __restrict__ in, float* __restrict__ out, int C) {
    __shared__ float tl[32][33];
    int v0 = blockIdx.x * 32, c0 = blockIdx.y * 32;
    int tx = threadIdx.x, ty = threadIdx.y;
#pragma unroll
    for (int i = 0; i < 4; i++) {
        int r = ty + 8 * i;
        int v = v0 + r;
        tl[r][tx] = (v < VV) ? in[(size_t)v * C + c0 + tx] : 0.f;
    }
    __syncthreads();
#pragma unroll
    for (int i = 0; i < 4; i++) {
        int r = ty + 8 * i;
        out[(size_t)(c0 + r) * VP + v0 + tx] = tl[tx][r];
    }
}

// ---------------- 6) fused scores ----------------
// 64 bt rows/block (bf16 staging, 128 KB dyn LDS), 4-way V split -> 256 blocks.
__device__ __forceinline__ void dot8(const unsigned short* __restrict__ F,
                                     const float* __restrict__ W, int nk4,
                                     float acc[8][8]) {
    for (int k4 = 0; k4 < nk4; k4++) {
        float zf[8][4];
#pragma unroll
        for (int i = 0; i < 8; i++) {
            ushort4 u = *(const ushort4*)(F + i * 512 + (k4 << 2));
            zf[i][0] = bf2f(u.x); zf[i][1] = bf2f(u.y);
            zf[i][2] = bf2f(u.z); zf[i][3] = bf2f(u.w);
        }
        const float* wk = W + (size_t)(k4 << 2) * VP;
#pragma unroll
        for (int kk = 0; kk < 4; kk++) {
            float4 w0 = *(const float4*)wk;
            float4 w1 = *(const float4*)(wk + 4);
            wk += VP;
#pragma unroll
            for (int i = 0; i < 8; i++) {
                acc[i][0] += zf[i][kk] * w0.x;
                acc[i][1] += zf[i][kk] * w0.y;
                acc[i][2] += zf[i][kk] * w0.z;
                acc[i][3] += zf[i][kk] * w0.w;
                acc[i][4] += zf[i][kk] * w1.x;
                acc[i][5] += zf[i][kk] * w1.y;
                acc[i][6] += zf[i][kk] * w1.z;
                acc[i][7] += zf[i][kk] * w1.w;
            }
        }
    }
}

__global__ __launch_bounds__(512) void k_scores(const float* __restrict__ h_all,
                                                const float* __restrict__ z,
                                                const float* __restrict__ P,
                                                const float* __restrict__ Q,
                                                const float* __restrict__ Gm,
                                                const float* __restrict__ cv,
                                                const float* __restrict__ b_prior,
                                                const float* __restrict__ b_gen,
                                                float* __restrict__ part) {
    extern __shared__ unsigned short sm[];
    unsigned short* hT = sm;             // 64 x 512 bf16
    unsigned short* fz = sm + 64 * 512;  // 64 x [z(256) | z^2(256)] bf16
    int tid = threadIdx.x;
    int bt0 = blockIdx.x * 64;
    int vbase = blockIdx.y * 2560;
    for (int i = tid; i < 8192; i += 512) {
        int r = i >> 7, c4 = i & 127;
        float4 v = *(const float4*)(h_all + (size_t)(bt0 + r) * 512 + (c4 << 2));
        *(ushort4*)(hT + r * 512 + (c4 << 2)) =
            make_ushort4(f2bf(v.x), f2bf(v.y), f2bf(v.z), f2bf(v.w));
    }
    for (int i = tid; i < 4096; i += 512) {
        int r = i >> 6, c4 = i & 63;
        float4 v = *(const float4*)(z + (size_t)(bt0 + r) * 256 + (c4 << 2));
        *(ushort4*)(fz + r * 512 + (c4 << 2)) =
            make_ushort4(f2bf(v.x), f2bf(v.y), f2bf(v.z), f2bf(v.w));
        *(ushort4*)(fz + r * 512 + 256 + (c4 << 2)) =
            make_ushort4(f2bf(v.x * v.x), f2bf(v.y * v.y), f2bf(v.z * v.z), f2bf(v.w * v.w));
    }
    __syncthreads();
    int w = tid >> 6, vl = tid & 63;
    const unsigned short* Fh = hT + (w * 8) * 512;
    const unsigned short* Fz = fz + (w * 8) * 512;
    float m1[8], s1[8], m2[8], s2[8], m3[8], s3[8];
#pragma unroll
    for (int i = 0; i < 8; i++) {
        m1[i] = m2[i] = m3[i] = -1e30f;
        s1[i] = s2[i] = s3[i] = 0.f;
    }
    for (int it = 0; it < 5; it++) {
        int v0 = vbase + it * 512 + vl * 8;
        float bp[8], bg[8], cvv[8];
#pragma unroll
        for (int j = 0; j < 8; j++) {
            int v = v0 + j;
            bool ok = v < VV;
            bp[j] = ok ? b_prior[v] : 0.f;
            bg[j] = ok ? b_gen[v] : 0.f;
            cvv[j] = ok ? cv[v] : 0.f;
        }
        // phase C: gen logits (K=256, z half of fz)
        {
            float acc[8][8] = {};
            dot8(Fz, Gm + v0, 64, acc);
            float u[8];
#pragma unroll
            for (int i = 0; i < 8; i++) {
#pragma unroll
                for (int j = 0; j < 8; j++)
                    u[j] = (v0 + j < VV) ? acc[i][j] + bg[j] : -1e30f;
                lse_upd8(m3[i], s3[i], u);
            }
        }
        // phase A: prior logits (K=512 on h)
        float accA[8][8] = {};
        dot8(Fh, P + v0, 128, accA);
        // phase B: lp body (K=512 on [z; z^2])
        float accB[8][8] = {};
        dot8(Fz, Q + v0, 128, accB);
        float u[8];
#pragma unroll
        for (int i = 0; i < 8; i++) {
#pragma unroll
            for (int j = 0; j < 8; j++)
                u[j] = (v0 + j < VV) ? accA[i][j] + bp[j] : -1e30f;
            lse_upd8(m1[i], s1[i], u);
#pragma unroll
            for (int j = 0; j < 8; j++)
                u[j] = (v0 + j < VV) ? u[j] + accB[i][j] + cvv[j] : -1e30f;
            lse_upd8(m2[i], s2[i], u);
        }
    }
#pragma unroll
    for (int off = 1; off < 64; off <<= 1) {
#pragma unroll
        for (int i = 0; i < 8; i++) {
            lse_red(m1[i], s1[i], off);
            lse_red(m2[i], s2[i], off);
            lse_red(m3[i], s3[i], off);
        }
    }
    if (vl == 0) {
        int base = blockIdx.y * 6;
#pragma unroll
        for (int i = 0; i < 8; i++) {
            int bt = bt0 + w * 8 + i;
            part[(base + 0) * 4096 + bt] = m1[i];
            part[(base + 1) * 4096 + bt] = s1[i];
            part[(base + 2) * 4096 + bt] = m2[i];
            part[(base + 3) * 4096 + bt] = s2[i];
            part[(base + 4) * 4096 + bt] = m3[i];
            part[(base + 5) * 4096 + bt] = s3[i];
        }
    }
}

// ---------------- 7) gx = z . w_gen[x] + b_gen[x] ----------------
__global__ void k_gx(const float* __restrict__ z, const int* __restrict__ x,
                     const float* __restrict__ w_gen, const float* __restrict__ b_gen,
                     float* __restrict__ gx) {
    int bt = blockIdx.x, k = threadIdx.x;
    int xi = x[bt];
    float p = z[bt * 256 + k] * w_gen[xi * 256 + k];
    __shared__ float red[256];
    red[k] = p;
    __syncthreads();
    for (int s = 128; s > 0; s >>= 1) {
        if (k < s) red[k] += red[k + s];
        __syncthreads();
    }
    if (k == 0) gx[bt] = red[0] + b_gen[xi];
}

// ---------------- 8) finalize (merge 4 V-split partials) ----------------
__device__ __forceinline__ float lse4(const float* __restrict__ part, int comp, int bt) {
    float M = -1e30f, S = 0.f;
#pragma unroll
    for (int vs = 0; vs < 4; vs++) {
        float m = part[(vs * 6 + comp) * 4096 + bt];
        float s = part[(vs * 6 + comp + 1) * 4096 + bt];
        float Mn = fmaxf(M, m);
        S = S * __expf(M - Mn) + s * __expf(m - Mn);
        M = Mn;
    }
    return M + logf(S);
}

__global__ void k_final(const float* __restrict__ part, const float* __restrict__ qz,
                        const float* __restrict__ gxv, const int* __restrict__ x_sl,
                        float* __restrict__ out) {
    int tid = threadIdx.x;
    float S = 0.f;
    for (int bt = tid; bt < 4096; bt += 256) {
        int b = bt >> 7, t = bt & 127;
        if (t < x_sl[b]) {
            float lse1 = lse4(part, 0, bt);
            float lse2 = lse4(part, 2, bt);
            float lse3 = lse4(part, 4, bt);
            float p_z = lse2 - lse1;
            float kl = qz[bt] - p_z;
            float px = gxv[bt] - lse3;
            S += px - kl;
        }
    }
    __shared__ float red[256];
    red[tid] = S;
    __syncthreads();
    for (int s = 128; s > 0; s >>= 1) {
        if (tid < s) red[tid] += red[tid + s];
        __syncthreads();
    }
    if (tid == 0) {
        int sl = 0;
        for (int b = 0; b < 32; b++) sl += x_sl[b];
        out[0] = -(red[0] / (float)sl);
    }
}

extern "C" void kernel_launch(void* const* d_in, const int* in_sizes, int n_in,
                              void* d_out, int out_size, void* d_ws, size_t ws_size,
                              hipStream_t stream) {
    const int* x = (const int*)d_in[0];
    const int* x_sl = (const int*)d_in[1];
    const float* eps = (const float*)d_in[2];
    const float* emb = (const float*)d_in[3];
    const float* w_ih = (const float*)d_in[4];
    const float* w_hh = (const float*)d_in[5];
    const float* b_ih = (const float*)d_in[6];
    const float* b_hh = (const float*)d_in[7];
    const float* w_prior = (const float*)d_in[8];
    const float* b_prior = (const float*)d_in[9];
    const float* w_gen = (const float*)d_in[10];
    const float* b_gen = (const float*)d_in[11];

    float* ws = (float*)d_ws;
    float* z = ws;
    float* qz = ws + 1048576;
    float* h_all = ws + 1052672;
    float* gx = ws + 3149824;
    float* part = ws + 3153920;
    float* region = ws + 3252224;
    float* xp = region;
    float* P = region;
    float* Q = region + 5242880;
    float* G = region + 10485760;
    float* cv = region + 13107200;

    k_embed<<<4096, 256, 0, stream>>>(x, x_sl, eps, emb, z, qz);
    k_xp<<<dim3(32, 64), 256, 0, stream>>>(z, w_ih, b_ih, b_hh, xp);
    {
        hipFuncSetAttribute((const void*)k_lstm, hipFuncAttributeMaxDynamicSharedMemorySize, 86016);
        void* args[] = {(void*)&xp, (void*)&w_hh, (void*)&h_all};
        hipLaunchCooperativeKernel((const void*)k_lstm, dim3(256), dim3(256), args, 86016, stream);
    }
    // xp dead; overlay P/Q/G/cv
    k_qconst<<<10000, 256, 0, stream>>>(emb, Q, cv);
    k_transpose<<<dim3(313, 16), dim3(32, 8), 0, stream>>>(w_prior, P, 512);
    k_transpose<<<dim3(313, 8), dim3(32, 8), 0, stream>>>(w_gen, G, 256);
    hipFuncSetAttribute((const void*)k_scores, hipFuncAttributeMaxDynamicSharedMemorySize, 131072);
    k_scores<<<dim3(64, 4), 512, 131072, stream>>>(h_all, z, P, Q, G, cv, b_prior, b_gen, part);
    k_gx<<<4096, 256, 0, stream>>>(z, x, w_gen, b_gen, gx);
    k_final<<<1, 256, 0, stream>>>(part, qz, gx, x_sl, (float*)d_out);
}

// Round 4
// 4777.206 us; speedup vs baseline: 2.4366x; 2.0073x over previous
//
#include <hip/hip_runtime.h>
#include <hip/hip_bf16.h>
#include <math.h>

// Sizes fixed by the problem
#define BB 32
#define TT 128
#define KK 256
#define HH 512
#define VV 10000
#define VP 10240
#define BT 4096           // B*T
#define HLOG2PI 0.91893853320467274178f

// ---- workspace layout (float offsets) ----
// z       : 0          1048576   (BT*K)
// qz      : 1048576    4096
// h_all   : 1052672    2097152   (BT*H)
// gx      : 3149824    4096
// part    : 3153920    98304     (4 vs * 6 * 4096)
// region  : 3252224    13117440  (xp overlaid by P,Q,G,cv)
//   xp    = region + 0        (8388608 = BT*4H)   [dead after k_lstm]
//   wpack = region + 8388608  (524288 floats = 2 MB bf16 w_hh) [alive: k_wpack..k_lstm;
//                              overwritten later by Q/G writes — they run after k_lstm]
//   P  = region + 0        (512*10240)   [after lstm]
//   Q  = region + 5242880  (512*10240)
//   G  = region + 10485760 (256*10240)
//   cv = region + 13107200 (10240)
// total 16,369,664 floats = 65.5 MB

__device__ __forceinline__ float softplus_b(float x) {
    float ax = fabsf(x);
    return fmaxf(x, 0.0f) + log2f(1.0f + exp2f(-ax));
}
__device__ __forceinline__ float sigm(float x) { return 1.0f / (1.0f + expf(-x)); }
__device__ __forceinline__ float bf2f(unsigned short u) {
    return __uint_as_float(((unsigned)u) << 16);
}
__device__ __forceinline__ unsigned short f2bf(float f) {
    unsigned u = __float_as_uint(f);
    u += 0x7FFFu + ((u >> 16) & 1u);
    return (unsigned short)(u >> 16);
}
__device__ __forceinline__ float blo(unsigned u) { return __uint_as_float(u << 16); }
__device__ __forceinline__ float bhi(unsigned u) { return __uint_as_float(u & 0xffff0000u); }
__device__ __forceinline__ void lse_upd8(float& m, float& s, const float* u) {
    float lm = u[0];
#pragma unroll
    for (int j = 1; j < 8; j++) lm = fmaxf(lm, u[j]);
    if (lm > m) { s *= __expf(m - lm); m = lm; }
    float a = 0.f;
#pragma unroll
    for (int j = 0; j < 8; j++) a += __expf(u[j] - m);
    s += a;
}
__device__ __forceinline__ void lse_red(float& m, float& s, int off) {
    float mo = __shfl_xor(m, off);
    float so = __shfl_xor(s, off);
    float mn = fmaxf(m, mo);
    s = s * __expf(m - mn) + so * __expf(mo - mn);
    m = mn;
}

// ---------------- 1) embedding -> z, q_z_lp ----------------
__global__ void k_embed(const int* __restrict__ x, const int* __restrict__ x_sl,
                        const float* __restrict__ eps, const float* __restrict__ emb,
                        float* __restrict__ z, float* __restrict__ qz) {
    int bt = blockIdx.x;
    int b = bt >> 7, t = bt & 127;
    int k = threadIdx.x;
    int xi = x[bt];
    float e1 = emb[xi * 512 + k];
    float sg = softplus_b(emb[xi * 512 + 256 + k]);
    float ep = eps[bt * 256 + k];
    float mk = (t < x_sl[b]) ? 1.f : 0.f;
    z[bt * 256 + k] = (e1 + sg * ep) * mk;
    float q = -HLOG2PI - logf(sg) - 0.5f * ep * ep;
    __shared__ float red[256];
    red[k] = q;
    __syncthreads();
    for (int s = 128; s > 0; s >>= 1) {
        if (k < s) red[k] += red[k + s];
        __syncthreads();
    }
    if (k == 0) qz[bt] = red[0];
}

// ---------------- 2) x_proj = z_shift @ w_ih^T + b_ih + b_hh ----------------
__global__ __launch_bounds__(256) void k_xp(const float* __restrict__ z,
                                            const float* __restrict__ w_ih,
                                            const float* __restrict__ b_ih,
                                            const float* __restrict__ b_hh,
                                            float* __restrict__ xp) {
    __shared__ float At[64][68];
    __shared__ float Wt[64][68];
    int n0 = blockIdx.x * 64, m0 = blockIdx.y * 64;
    int tid = threadIdx.x;
    int tn = tid & 15, tm = tid >> 4;
    float acc[4][4] = {};
    for (int kc = 0; kc < 256; kc += 64) {
        __syncthreads();
        for (int i = tid; i < 1024; i += 256) {
            int r = i >> 4, c4 = i & 15;
            int bt = m0 + r;
            int t = bt & 127;
            float4 v = make_float4(0.f, 0.f, 0.f, 0.f);
            if (t > 0) v = *(const float4*)(z + (bt - 1) * 256 + kc + c4 * 4);
            *(float4*)&At[r][c4 * 4] = v;
        }
        for (int i = tid; i < 1024; i += 256) {
            int r = i >> 4, c4 = i & 15;
            float4 v = *(const float4*)(w_ih + (n0 + r) * 256 + kc + c4 * 4);
            *(float4*)&Wt[r][c4 * 4] = v;
        }
        __syncthreads();
        for (int kk = 0; kk < 16; kk++) {
            float4 a[4], w[4];
#pragma unroll
            for (int i = 0; i < 4; i++) a[i] = *(const float4*)&At[tm + 16 * i][kk * 4];
#pragma unroll
            for (int j = 0; j < 4; j++) w[j] = *(const float4*)&Wt[tn + 16 * j][kk * 4];
#pragma unroll
            for (int i = 0; i < 4; i++)
#pragma unroll
                for (int j = 0; j < 4; j++)
                    acc[i][j] += a[i].x * w[j].x + a[i].y * w[j].y + a[i].z * w[j].z + a[i].w * w[j].w;
        }
    }
#pragma unroll
    for (int i = 0; i < 4; i++) {
        int m = m0 + tm + 16 * i;
#pragma unroll
        for (int j = 0; j < 4; j++) {
            int n = n0 + tn + 16 * j;
            xp[m * 2048 + n] = acc[i][j] + b_ih[n] + b_hh[n];
        }
    }
}

// ---------------- 2b) pack w_hh -> bf16, layout [k4][j][g] of ushort4 ----------------
// ushort4 unit index o = (k4*512 + j)*4 + g holds w_hh[g*512+j][4*k4 .. 4*k4+3].
__global__ __launch_bounds__(256) void k_wpack(const float* __restrict__ w_hh,
                                               ushort* __restrict__ wp) {
    int o = blockIdx.x * 256 + threadIdx.x;  // 0 .. 262143
    int g = o & 3;
    int j = (o >> 2) & 511;
    int k4 = o >> 11;
    const float* src = w_hh + (size_t)(g * 512 + j) * 512 + (k4 << 2);
    ushort4 u = make_ushort4(f2bf(src[0]), f2bf(src[1]), f2bf(src[2]), f2bf(src[3]));
    *(ushort4*)(wp + (size_t)o * 4) = u;
}

// ---------------- 3) LSTM recurrence: one block per batch element ----------------
// 32 blocks x 512 threads, NORMAL launch, zero cross-block communication.
// Thread j owns h-unit j of its sequence: h_prev in block LDS (broadcast reads),
// c in a register. Weights stream from L2 (bf16-packed, 2 MB/step/CU, coalesced
// 32 B/thread/k4). Per step ~= max(load 6.8us, valu ~7us) on each of 32 CUs.
__global__ __launch_bounds__(512) void k_lstm(const float* __restrict__ xp,
                                              const ushort* __restrict__ wp,
                                              float* __restrict__ h_all) {
    __shared__ float hs[512];
    int b = blockIdx.x;
    int j = threadIdx.x;
    hs[j] = 0.f;
    __syncthreads();
    float c = 0.f;
    const uint4* wr = (const uint4*)wp + (size_t)j * 2;  // per-k4 stride = 1024 uint4
    for (int t = 0; t < 128; t++) {
        const float* xpr = xp + (size_t)((b << 7) + t) * 2048 + j;
        float g0 = xpr[0], g1 = xpr[512], g2 = xpr[1024], g3 = xpr[1536];
        if (t > 0) {
            float a0 = 0.f, a1 = 0.f, a2 = 0.f, a3 = 0.f;
#pragma unroll 8
            for (int k4 = 0; k4 < 128; k4++) {
                float4 h4 = *(const float4*)&hs[k4 << 2];
                uint4 A = wr[k4 * 1024 + 0];  // gates 0,1 (8 bf16)
                uint4 B = wr[k4 * 1024 + 1];  // gates 2,3
                a0 += blo(A.x) * h4.x + bhi(A.x) * h4.y + blo(A.y) * h4.z + bhi(A.y) * h4.w;
                a1 += blo(A.z) * h4.x + bhi(A.z) * h4.y + blo(A.w) * h4.z + bhi(A.w) * h4.w;
                a2 += blo(B.x) * h4.x + bhi(B.x) * h4.y + blo(B.y) * h4.z + bhi(B.y) * h4.w;
                a3 += blo(B.z) * h4.x + bhi(B.z) * h4.y + blo(B.w) * h4.z + bhi(B.w) * h4.w;
            }
            g0 += a0; g1 += a1; g2 += a2; g3 += a3;
        }
        c = sigm(g1) * c + sigm(g0) * tanhf(g2);
        float h = sigm(g3) * tanhf(c);
        __syncthreads();  // all reads of old hs done
        hs[j] = h;
        h_all[(size_t)((b << 7) + t) * 512 + j] = h;
        __syncthreads();
    }
}

// ---------------- 4) prior Q ([a; -inv2var]^T) + const_v ----------------
__global__ void k_qconst(const float* __restrict__ emb, float* __restrict__ Q,
                         float* __restrict__ cv) {
    int v = blockIdx.x, k = threadIdx.x;
    float mu = emb[v * 512 + k];
    float sg = softplus_b(emb[v * 512 + 256 + k]);
    float iv = 0.5f / (sg * sg);
    Q[(size_t)k * VP + v] = 2.f * iv * mu;
    Q[(size_t)(256 + k) * VP + v] = -iv;
    float ct = -HLOG2PI - logf(sg) - mu * mu * iv;
    __shared__ float red[256];
    red[k] = ct;
    __syncthreads();
    for (int s = 128; s > 0; s >>= 1) {
        if (k < s) red[k] += red[k + s];
        __syncthreads();
    }
    if (k == 0) cv[v] = red[0];
}

// ---------------- 5) transpose (V x C) -> (C x VP) ----------------
__global__ void k_transpose(const float* __restrict__ in, float* __restrict__ out, int C) {
    __shared__ float tl[32][33];
    int v0 = blockIdx.x * 32, c0 = blockIdx.y * 32;
    int tx = threadIdx.x, ty = threadIdx.y;
#pragma unroll
    for (int i = 0; i < 4; i++) {
        int r = ty + 8 * i;
        int v = v0 + r;
        tl[r][tx] = (v < VV) ? in[(size_t)v * C + c0 + tx] : 0.f;
    }
    __syncthreads();
#pragma unroll
    for (int i = 0; i < 4; i++) {
        int r = ty + 8 * i;
        out[(size_t)(c0 + r) * VP + v0 + tx] = tl[tx][r];
    }
}

// ---------------- 6) fused scores ----------------
// 64 bt rows/block (bf16 staging, 128 KB dyn LDS), 4-way V split -> 256 blocks.
__device__ __forceinline__ void dot8(const unsigned short* __restrict__ F,
                                     const float* __restrict__ W, int nk4,
                                     float acc[8][8]) {
    for (int k4 = 0; k4 < nk4; k4++) {
        float zf[8][4];
#pragma unroll
        for (int i = 0; i < 8; i++) {
            ushort4 u = *(const ushort4*)(F + i * 512 + (k4 << 2));
            zf[i][0] = bf2f(u.x); zf[i][1] = bf2f(u.y);
            zf[i][2] = bf2f(u.z); zf[i][3] = bf2f(u.w);
        }
        const float* wk = W + (size_t)(k4 << 2) * VP;
#pragma unroll
        for (int kk = 0; kk < 4; kk++) {
            float4 w0 = *(const float4*)wk;
            float4 w1 = *(const float4*)(wk + 4);
            wk += VP;
#pragma unroll
            for (int i = 0; i < 8; i++) {
                acc[i][0] += zf[i][kk] * w0.x;
                acc[i][1] += zf[i][kk] * w0.y;
                acc[i][2] += zf[i][kk] * w0.z;
                acc[i][3] += zf[i][kk] * w0.w;
                acc[i][4] += zf[i][kk] * w1.x;
                acc[i][5] += zf[i][kk] * w1.y;
                acc[i][6] += zf[i][kk] * w1.z;
                acc[i][7] += zf[i][kk] * w1.w;
            }
        }
    }
}

__global__ __launch_bounds__(512) void k_scores(const float* __restrict__ h_all,
                                                const float* __restrict__ z,
                                                const float* __restrict__ P,
                                                const float* __restrict__ Q,
                                                const float* __restrict__ Gm,
                                                const float* __restrict__ cv,
                                                const float* __restrict__ b_prior,
                                                const float* __restrict__ b_gen,
                                                float* __restrict__ part) {
    extern __shared__ unsigned short sm[];
    unsigned short* hT = sm;             // 64 x 512 bf16
    unsigned short* fz = sm + 64 * 512;  // 64 x [z(256) | z^2(256)] bf16
    int tid = threadIdx.x;
    int bt0 = blockIdx.x * 64;
    int vbase = blockIdx.y * 2560;
    for (int i = tid; i < 8192; i += 512) {
        int r = i >> 7, c4 = i & 127;
        float4 v = *(const float4*)(h_all + (size_t)(bt0 + r) * 512 + (c4 << 2));
        *(ushort4*)(hT + r * 512 + (c4 << 2)) =
            make_ushort4(f2bf(v.x), f2bf(v.y), f2bf(v.z), f2bf(v.w));
    }
    for (int i = tid; i < 4096; i += 512) {
        int r = i >> 6, c4 = i & 63;
        float4 v = *(const float4*)(z + (size_t)(bt0 + r) * 256 + (c4 << 2));
        *(ushort4*)(fz + r * 512 + (c4 << 2)) =
            make_ushort4(f2bf(v.x), f2bf(v.y), f2bf(v.z), f2bf(v.w));
        *(ushort4*)(fz + r * 512 + 256 + (c4 << 2)) =
            make_ushort4(f2bf(v.x * v.x), f2bf(v.y * v.y), f2bf(v.z * v.z), f2bf(v.w * v.w));
    }
    __syncthreads();
    int w = tid >> 6, vl = tid & 63;
    const unsigned short* Fh = hT + (w * 8) * 512;
    const unsigned short* Fz = fz + (w * 8) * 512;
    float m1[8], s1[8], m2[8], s2[8], m3[8], s3[8];
#pragma unroll
    for (int i = 0; i < 8; i++) {
        m1[i] = m2[i] = m3[i] = -1e30f;
        s1[i] = s2[i] = s3[i] = 0.f;
    }
    for (int it = 0; it < 5; it++) {
        int v0 = vbase + it * 512 + vl * 8;
        float bp[8], bg[8], cvv[8];
#pragma unroll
        for (int j = 0; j < 8; j++) {
            int v = v0 + j;
            bool ok = v < VV;
            bp[j] = ok ? b_prior[v] : 0.f;
            bg[j] = ok ? b_gen[v] : 0.f;
            cvv[j] = ok ? cv[v] : 0.f;
        }
        // phase C: gen logits (K=256, z half of fz)
        {
            float acc[8][8] = {};
            dot8(Fz, Gm + v0, 64, acc);
            float u[8];
#pragma unroll
            for (int i = 0; i < 8; i++) {
#pragma unroll
                for (int j = 0; j < 8; j++)
                    u[j] = (v0 + j < VV) ? acc[i][j] + bg[j] : -1e30f;
                lse_upd8(m3[i], s3[i], u);
            }
        }
        // phase A: prior logits (K=512 on h)
        float accA[8][8] = {};
        dot8(Fh, P + v0, 128, accA);
        // phase B: lp body (K=512 on [z; z^2])
        float accB[8][8] = {};
        dot8(Fz, Q + v0, 128, accB);
        float u[8];
#pragma unroll
        for (int i = 0; i < 8; i++) {
#pragma unroll
            for (int j = 0; j < 8; j++)
                u[j] = (v0 + j < VV) ? accA[i][j] + bp[j] : -1e30f;
            lse_upd8(m1[i], s1[i], u);
#pragma unroll
            for (int j = 0; j < 8; j++)
                u[j] = (v0 + j < VV) ? u[j] + accB[i][j] + cvv[j] : -1e30f;
            lse_upd8(m2[i], s2[i], u);
        }
    }
#pragma unroll
    for (int off = 1; off < 64; off <<= 1) {
#pragma unroll
        for (int i = 0; i < 8; i++) {
            lse_red(m1[i], s1[i], off);
            lse_red(m2[i], s2[i], off);
            lse_red(m3[i], s3[i], off);
        }
    }
    if (vl == 0) {
        int base = blockIdx.y * 6;
#pragma unroll
        for (int i = 0; i < 8; i++) {
            int bt = bt0 + w * 8 + i;
            part[(base + 0) * 4096 + bt] = m1[i];
            part[(base + 1) * 4096 + bt] = s1[i];
            part[(base + 2) * 4096 + bt] = m2[i];
            part[(base + 3) * 4096 + bt] = s2[i];
            part[(base + 4) * 4096 + bt] = m3[i];
            part[(base + 5) * 4096 + bt] = s3[i];
        }
    }
}

// ---------------- 7) gx = z . w_gen[x] + b_gen[x] ----------------
__global__ void k_gx(const float* __restrict__ z, const int* __restrict__ x,
                     const float* __restrict__ w_gen, const float* __restrict__ b_gen,
                     float* __restrict__ gx) {
    int bt = blockIdx.x, k = threadIdx.x;
    int xi = x[bt];
    float p = z[bt * 256 + k] * w_gen[xi * 256 + k];
    __shared__ float red[256];
    red[k] = p;
    __syncthreads();
    for (int s = 128; s > 0; s >>= 1) {
        if (k < s) red[k] += red[k + s];
        __syncthreads();
    }
    if (k == 0) gx[bt] = red[0] + b_gen[xi];
}

// ---------------- 8) finalize (merge 4 V-split partials) ----------------
__device__ __forceinline__ float lse4(const float* __restrict__ part, int comp, int bt) {
    float M = -1e30f, S = 0.f;
#pragma unroll
    for (int vs = 0; vs < 4; vs++) {
        float m = part[(vs * 6 + comp) * 4096 + bt];
        float s = part[(vs * 6 + comp + 1) * 4096 + bt];
        float Mn = fmaxf(M, m);
        S = S * __expf(M - Mn) + s * __expf(m - Mn);
        M = Mn;
    }
    return M + logf(S);
}

__global__ void k_final(const float* __restrict__ part, const float* __restrict__ qz,
                        const float* __restrict__ gxv, const int* __restrict__ x_sl,
                        float* __restrict__ out) {
    int tid = threadIdx.x;
    float S = 0.f;
    for (int bt = tid; bt < 4096; bt += 256) {
        int b = bt >> 7, t = bt & 127;
        if (t < x_sl[b]) {
            float lse1 = lse4(part, 0, bt);
            float lse2 = lse4(part, 2, bt);
            float lse3 = lse4(part, 4, bt);
            float p_z = lse2 - lse1;
            float kl = qz[bt] - p_z;
            float px = gxv[bt] - lse3;
            S += px - kl;
        }
    }
    __shared__ float red[256];
    red[tid] = S;
    __syncthreads();
    for (int s = 128; s > 0; s >>= 1) {
        if (tid < s) red[tid] += red[tid + s];
        __syncthreads();
    }
    if (tid == 0) {
        int sl = 0;
        for (int b = 0; b < 32; b++) sl += x_sl[b];
        out[0] = -(red[0] / (float)sl);
    }
}

extern "C" void kernel_launch(void* const* d_in, const int* in_sizes, int n_in,
                              void* d_out, int out_size, void* d_ws, size_t ws_size,
                              hipStream_t stream) {
    const int* x = (const int*)d_in[0];
    const int* x_sl = (const int*)d_in[1];
    const float* eps = (const float*)d_in[2];
    const float* emb = (const float*)d_in[3];
    const float* w_ih = (const float*)d_in[4];
    const float* w_hh = (const float*)d_in[5];
    const float* b_ih = (const float*)d_in[6];
    const float* b_hh = (const float*)d_in[7];
    const float* w_prior = (const float*)d_in[8];
    const float* b_prior = (const float*)d_in[9];
    const float* w_gen = (const float*)d_in[10];
    const float* b_gen = (const float*)d_in[11];

    float* ws = (float*)d_ws;
    float* z = ws;
    float* qz = ws + 1048576;
    float* h_all = ws + 1052672;
    float* gx = ws + 3149824;
    float* part = ws + 3153920;
    float* region = ws + 3252224;
    float* xp = region;
    ushort* wpack = (ushort*)(region + 8388608);
    float* P = region;
    float* Q = region + 5242880;
    float* G = region + 10485760;
    float* cv = region + 13107200;

    k_embed<<<4096, 256, 0, stream>>>(x, x_sl, eps, emb, z, qz);
    k_xp<<<dim3(32, 64), 256, 0, stream>>>(z, w_ih, b_ih, b_hh, xp);
    k_wpack<<<1024, 256, 0, stream>>>(w_hh, wpack);
    k_lstm<<<32, 512, 0, stream>>>(xp, wpack, h_all);
    // xp and wpack dead; overlay P/Q/G/cv
    k_qconst<<<10000, 256, 0, stream>>>(emb, Q, cv);
    k_transpose<<<dim3(313, 16), dim3(32, 8), 0, stream>>>(w_prior, P, 512);
    k_transpose<<<dim3(313, 8), dim3(32, 8), 0, stream>>>(w_gen, G, 256);
    hipFuncSetAttribute((const void*)k_scores, hipFuncAttributeMaxDynamicSharedMemorySize, 131072);
    k_scores<<<dim3(64, 4), 512, 131072, stream>>>(h_all, z, P, Q, G, cv, b_prior, b_gen, part);
    k_gx<<<4096, 256, 0, stream>>>(z, x, w_gen, b_gen, gx);
    k_final<<<1, 256, 0, stream>>>(part, qz, gx, x_sl, (float*)d_out);
}

// Round 5
// 2403.362 us; speedup vs baseline: 4.8433x; 1.9877x over previous
//
#include <hip/hip_runtime.h>
#include <hip/hip_bf16.h>
#include <math.h>

// Sizes fixed by the problem
#define BB 32
#define TT 128
#define KK 256
#define HH 512
#define VV 10000
#define VP 10240
#define BT 4096           // B*T
#define HLOG2PI 0.91893853320467274178f

// ---- workspace layout (float offsets) ----
// z       : 0          1048576   (BT*K)
// qz      : 1048576    4096
// h_all   : 1052672    2097152   (BT*H)
// gx      : 3149824    4096
// part    : 3153920    98304     (4 vs * 6 * 4096)
// region  : 3252224    13117440
//   xp    = region + 0        (8388608 = BT*4H)   [dead after k_lstm]
//   wpIF  = region + 8388608  (262144 floats = 1 MB f16)  [alive k_wpack2..k_lstm]
//   wpGO  = region + 8650752  (262144 floats = 1 MB f16)
//   flags = region + 13107200 (256 ints; dead after k_lstm, overwritten by cv)
//   P  = region + 0        (512*10240)   [after lstm]
//   Q  = region + 5242880  (512*10240)
//   G  = region + 10485760 (256*10240)
//   cv = region + 13107200 (10240)
// total 16,369,664 floats = 65.5 MB

__device__ __forceinline__ float softplus_b(float x) {
    float ax = fabsf(x);
    return fmaxf(x, 0.0f) + log2f(1.0f + exp2f(-ax));
}
__device__ __forceinline__ float sigm(float x) { return 1.0f / (1.0f + expf(-x)); }
__device__ __forceinline__ float bf2f(unsigned short u) {
    return __uint_as_float(((unsigned)u) << 16);
}
__device__ __forceinline__ unsigned short f2bf(float f) {
    unsigned u = __float_as_uint(f);
    u += 0x7FFFu + ((u >> 16) & 1u);
    return (unsigned short)(u >> 16);
}
typedef _Float16 h2f16 __attribute__((ext_vector_type(2)));
__device__ __forceinline__ unsigned pkh2(float a, float b) {
    h2f16 h;
    h.x = (_Float16)a;
    h.y = (_Float16)b;
    return *(unsigned*)&h;
}
__device__ __forceinline__ float fdot2u(unsigned a, unsigned b, float c) {
    h2f16 ah = *(h2f16*)&a, bh = *(h2f16*)&b;
#if __has_builtin(__builtin_amdgcn_fdot2)
    return __builtin_amdgcn_fdot2(ah, bh, c, false);
#else
    return c + (float)ah.x * (float)bh.x + (float)ah.y * (float)bh.y;
#endif
}
__device__ __forceinline__ void lse_upd8(float& m, float& s, const float* u) {
    float lm = u[0];
#pragma unroll
    for (int j = 1; j < 8; j++) lm = fmaxf(lm, u[j]);
    if (lm > m) { s *= __expf(m - lm); m = lm; }
    float a = 0.f;
#pragma unroll
    for (int j = 0; j < 8; j++) a += __expf(u[j] - m);
    s += a;
}
__device__ __forceinline__ void lse_red(float& m, float& s, int off) {
    float mo = __shfl_xor(m, off);
    float so = __shfl_xor(s, off);
    float mn = fmaxf(m, mo);
    s = s * __expf(m - mn) + so * __expf(mo - mn);
    m = mn;
}

// ---------------- 1) embedding -> z, q_z_lp ----------------
__global__ void k_embed(const int* __restrict__ x, const int* __restrict__ x_sl,
                        const float* __restrict__ eps, const float* __restrict__ emb,
                        float* __restrict__ z, float* __restrict__ qz) {
    int bt = blockIdx.x;
    int b = bt >> 7, t = bt & 127;
    int k = threadIdx.x;
    int xi = x[bt];
    float e1 = emb[xi * 512 + k];
    float sg = softplus_b(emb[xi * 512 + 256 + k]);
    float ep = eps[bt * 256 + k];
    float mk = (t < x_sl[b]) ? 1.f : 0.f;
    z[bt * 256 + k] = (e1 + sg * ep) * mk;
    float q = -HLOG2PI - logf(sg) - 0.5f * ep * ep;
    __shared__ float red[256];
    red[k] = q;
    __syncthreads();
    for (int s = 128; s > 0; s >>= 1) {
        if (k < s) red[k] += red[k + s];
        __syncthreads();
    }
    if (k == 0) qz[bt] = red[0];
}

// ---------------- 2) x_proj = z_shift @ w_ih^T + b_ih + b_hh ----------------
__global__ __launch_bounds__(256) void k_xp(const float* __restrict__ z,
                                            const float* __restrict__ w_ih,
                                            const float* __restrict__ b_ih,
                                            const float* __restrict__ b_hh,
                                            float* __restrict__ xp) {
    __shared__ float At[64][68];
    __shared__ float Wt[64][68];
    int n0 = blockIdx.x * 64, m0 = blockIdx.y * 64;
    int tid = threadIdx.x;
    int tn = tid & 15, tm = tid >> 4;
    float acc[4][4] = {};
    for (int kc = 0; kc < 256; kc += 64) {
        __syncthreads();
        for (int i = tid; i < 1024; i += 256) {
            int r = i >> 4, c4 = i & 15;
            int bt = m0 + r;
            int t = bt & 127;
            float4 v = make_float4(0.f, 0.f, 0.f, 0.f);
            if (t > 0) v = *(const float4*)(z + (bt - 1) * 256 + kc + c4 * 4);
            *(float4*)&At[r][c4 * 4] = v;
        }
        for (int i = tid; i < 1024; i += 256) {
            int r = i >> 4, c4 = i & 15;
            float4 v = *(const float4*)(w_ih + (n0 + r) * 256 + kc + c4 * 4);
            *(float4*)&Wt[r][c4 * 4] = v;
        }
        __syncthreads();
        for (int kk = 0; kk < 16; kk++) {
            float4 a[4], w[4];
#pragma unroll
            for (int i = 0; i < 4; i++) a[i] = *(const float4*)&At[tm + 16 * i][kk * 4];
#pragma unroll
            for (int j = 0; j < 4; j++) w[j] = *(const float4*)&Wt[tn + 16 * j][kk * 4];
#pragma unroll
            for (int i = 0; i < 4; i++)
#pragma unroll
                for (int j = 0; j < 4; j++)
                    acc[i][j] += a[i].x * w[j].x + a[i].y * w[j].y + a[i].z * w[j].z + a[i].w * w[j].w;
        }
    }
#pragma unroll
    for (int i = 0; i < 4; i++) {
        int m = m0 + tm + 16 * i;
#pragma unroll
        for (int j = 0; j < 4; j++) {
            int n = n0 + tn + 16 * j;
            xp[m * 2048 + n] = acc[i][j] + b_ih[n] + b_hh[n];
        }
    }
}

// ---------------- 2b) pack w_hh -> f16 pairs for the j-partitioned LSTM ----------------
// wpIF[m][k4 0..127][j 0..63] uint4 = (i_k01, i_k23, f_k01, f_k23)
// wpGO[m][kh 0..3][q 0..31][j 0..63] uint4 = (g_k01, g_k23, o_k01, o_k23), k4 = kh*32+q
__global__ __launch_bounds__(256) void k_wpack2(const float* __restrict__ w_hh,
                                                uint4* __restrict__ wpIF,
                                                uint4* __restrict__ wpGO) {
    int o = blockIdx.x * 256 + threadIdx.x;  // 0..65535
    if (blockIdx.y == 0) {
        int j = o & 63, k4 = (o >> 6) & 127, m = o >> 13;
        const float* wi = w_hh + (size_t)((m << 6) + j) * 512 + (k4 << 2);
        const float* wf = w_hh + (size_t)(512 + (m << 6) + j) * 512 + (k4 << 2);
        uint4 u;
        u.x = pkh2(wi[0], wi[1]); u.y = pkh2(wi[2], wi[3]);
        u.z = pkh2(wf[0], wf[1]); u.w = pkh2(wf[2], wf[3]);
        wpIF[o] = u;
    } else {
        int j = o & 63, q = (o >> 6) & 31, kh = (o >> 11) & 3, m = o >> 13;
        int k4 = (kh << 5) + q;
        const float* wg = w_hh + (size_t)(1024 + (m << 6) + j) * 512 + (k4 << 2);
        const float* wo = w_hh + (size_t)(1536 + (m << 6) + j) * 512 + (k4 << 2);
        uint4 u;
        u.x = pkh2(wg[0], wg[1]); u.y = pkh2(wg[2], wg[3]);
        u.z = pkh2(wo[0], wo[1]); u.w = pkh2(wo[2], wo[3]);
        wpGO[o] = u;
    }
}

// ---------------- 3) LSTM: 8 j-slice blocks per batch element ----------------
// 256 blocks x 256 threads, cooperative (co-residency guarantee). Block = (m,b):
// m = j-slice (64 h-units), b = batch. Weights RESIDENT: gates i,f in 128 KB LDS,
// gates g,o in 32 uint4 VGPRs/thread. Per-step h exchange among the 8 group
// members via agent-scope atomics: 64 h stores + release flag; consumers poll
// 8 flags relaxed then gather 512 h. Group members are = b (mod 32) -> same XCD
// under %8 dispatch (locality only; atomics give correctness regardless).
__global__ __launch_bounds__(256, 1) void k_lstm(const float* __restrict__ xp,
                                                 const uint4* __restrict__ wpIF,
                                                 const uint4* __restrict__ wpGO,
                                                 float* __restrict__ h_all,
                                                 int* __restrict__ flag) {
    extern __shared__ char smc[];
    uint4* wif = (uint4*)smc;                   // [k4 128][j 64] = 128 KB
    unsigned* hs2 = (unsigned*)(smc + 131072);  // 256 f16-pairs of h_prev
    float* red = (float*)(smc + 132096);        // [4 gates][4 kh][64 j]
    int bid = blockIdx.x;
    int b = bid & 31;
    int m = bid >> 5;
    int tid = threadIdx.x;
    int j = tid & 63, kh = tid >> 6;
    const uint4* srcIF = wpIF + ((size_t)m << 13);
    for (int i = tid; i < 8192; i += 256) wif[i] = srcIF[i];
    uint4 wgo[32];
    const uint4* srcGO = wpGO + ((((size_t)m << 2) + kh) << 11) + j;
#pragma unroll
    for (int q = 0; q < 32; q++) wgo[q] = srcGO[q << 6];
    float c = 0.f;
    int* hall_i = (int*)h_all;
    __syncthreads();
    for (int t = 0; t < 128; t++) {
        float a0 = 0.f, a1 = 0.f, a2 = 0.f, a3 = 0.f;
        if (t > 0) {
            if (tid < 8) {
                while (__hip_atomic_load(&flag[(b << 3) + tid], __ATOMIC_RELAXED,
                                         __HIP_MEMORY_SCOPE_AGENT) < t) {}
            }
            __syncthreads();
            {
                const int* hp = hall_i + (size_t)((b << 7) + t - 1) * 512 + (tid << 1);
                int u0 = __hip_atomic_load(hp, __ATOMIC_RELAXED, __HIP_MEMORY_SCOPE_AGENT);
                int u1 = __hip_atomic_load(hp + 1, __ATOMIC_RELAXED, __HIP_MEMORY_SCOPE_AGENT);
                hs2[tid] = pkh2(__int_as_float(u0), __int_as_float(u1));
            }
            __syncthreads();
            const uint4* wl = wif + ((kh << 5) << 6) + j;
            const unsigned* hp2 = hs2 + (kh << 6);
#pragma unroll
            for (int q = 0; q < 32; q++) {
                uint4 A = wl[q << 6];
                uint4 B = wgo[q];
                unsigned p0 = hp2[(q << 1)];
                unsigned p1 = hp2[(q << 1) + 1];
                a0 = fdot2u(A.x, p0, a0); a0 = fdot2u(A.y, p1, a0);
                a1 = fdot2u(A.z, p0, a1); a1 = fdot2u(A.w, p1, a1);
                a2 = fdot2u(B.x, p0, a2); a2 = fdot2u(B.y, p1, a2);
                a3 = fdot2u(B.z, p0, a3); a3 = fdot2u(B.w, p1, a3);
            }
        }
        red[(0 * 4 + kh) * 64 + j] = a0;
        red[(1 * 4 + kh) * 64 + j] = a1;
        red[(2 * 4 + kh) * 64 + j] = a2;
        red[(3 * 4 + kh) * 64 + j] = a3;
        __syncthreads();
        if (tid < 64) {  // wave 0 exactly: owns h-unit jg, holds c
            int jg = (m << 6) + tid;
            const float* xpr = xp + (size_t)((b << 7) + t) * 2048 + jg;
            float g0 = xpr[0], g1 = xpr[512], g2 = xpr[1024], g3 = xpr[1536];
#pragma unroll
            for (int q = 0; q < 4; q++) {
                g0 += red[(0 * 4 + q) * 64 + tid];
                g1 += red[(1 * 4 + q) * 64 + tid];
                g2 += red[(2 * 4 + q) * 64 + tid];
                g3 += red[(3 * 4 + q) * 64 + tid];
            }
            c = sigm(g1) * c + sigm(g0) * tanhf(g2);
            float h = sigm(g3) * tanhf(c);
            __hip_atomic_store(hall_i + (size_t)((b << 7) + t) * 512 + jg, __float_as_int(h),
                               __ATOMIC_RELAXED, __HIP_MEMORY_SCOPE_AGENT);
            if (tid == 0)  // same wave as the h stores: release waitcnt covers them
                __hip_atomic_store(&flag[(b << 3) + m], t + 1, __ATOMIC_RELEASE,
                                   __HIP_MEMORY_SCOPE_AGENT);
        }
        __syncthreads();
    }
}

// ---------------- 4a) const_v ----------------
__global__ void k_cv(const float* __restrict__ emb, float* __restrict__ cv) {
    int v = blockIdx.x, k = threadIdx.x;
    float mu = emb[v * 512 + k];
    float sg = softplus_b(emb[v * 512 + 256 + k]);
    float iv = 0.5f / (sg * sg);
    float ct = -HLOG2PI - logf(sg) - mu * mu * iv;
    __shared__ float red[256];
    red[k] = ct;
    __syncthreads();
    for (int s = 128; s > 0; s >>= 1) {
        if (k < s) red[k] += red[k + s];
        __syncthreads();
    }
    if (k == 0) cv[v] = red[0];
}

// ---------------- 4b) prior Q ([a; -inv2var]^T), coalesced via LDS tile ----------------
__global__ void k_qt(const float* __restrict__ emb, float* __restrict__ Q) {
    __shared__ float ta[32][33], tb[32][33];
    int v0 = blockIdx.x * 32, k0 = blockIdx.y * 32;
    int tx = threadIdx.x, ty = threadIdx.y;
#pragma unroll
    for (int i = 0; i < 4; i++) {
        int r = ty + 8 * i;
        int v = v0 + r;
        float mu = 0.f, sge = 0.f;
        if (v < VV) {
            mu = emb[(size_t)v * 512 + k0 + tx];
            sge = emb[(size_t)v * 512 + 256 + k0 + tx];
        }
        float sg = softplus_b(sge);
        float iv = 0.5f / (sg * sg);
        ta[r][tx] = 2.f * iv * mu;
        tb[r][tx] = -iv;
    }
    __syncthreads();
#pragma unroll
    for (int i = 0; i < 4; i++) {
        int r = ty + 8 * i;
        int k = k0 + r;
        if (v0 + tx < VV) {
            Q[(size_t)k * VP + v0 + tx] = ta[tx][r];
            Q[(size_t)(256 + k) * VP + v0 + tx] = tb[tx][r];
        }
    }
}

// ---------------- 5) transpose (V x C) -> (C x VP) ----------------
__global__ void k_transpose(const float* __restrict__ in, float* __restrict__ out, int C) {
    __shared__ float tl[32][33];
    int v0 = blockIdx.x * 32, c0 = blockIdx.y * 32;
    int tx = threadIdx.x, ty = threadIdx.y;
#pragma unroll
    for (int i = 0; i < 4; i++) {
        int r = ty + 8 * i;
        int v = v0 + r;
        tl[r][tx] = (v < VV) ? in[(size_t)v * C + c0 + tx] : 0.f;
    }
    __syncthreads();
#pragma unroll
    for (int i = 0; i < 4; i++) {
        int r = ty + 8 * i;
        out[(size_t)(c0 + r) * VP + v0 + tx] = tl[tx][r];
    }
}

// ---------------- 6) fused scores ----------------
// 64 bt rows/block (bf16 staging, 128 KB dyn LDS), 4-way V split -> 256 blocks.
__device__ __forceinline__ void dot8(const unsigned short* __restrict__ F,
                                     const float* __restrict__ W, int nk4,
                                     float acc[8][8]) {
    for (int k4 = 0; k4 < nk4; k4++) {
        float zf[8][4];
#pragma unroll
        for (int i = 0; i < 8; i++) {
            ushort4 u = *(const ushort4*)(F + i * 512 + (k4 << 2));
            zf[i][0] = bf2f(u.x); zf[i][1] = bf2f(u.y);
            zf[i][2] = bf2f(u.z); zf[i][3] = bf2f(u.w);
        }
        const float* wk = W + (size_t)(k4 << 2) * VP;
#pragma unroll
        for (int kk = 0; kk < 4; kk++) {
            float4 w0 = *(const float4*)wk;
            float4 w1 = *(const float4*)(wk + 4);
            wk += VP;
#pragma unroll
            for (int i = 0; i < 8; i++) {
                acc[i][0] += zf[i][kk] * w0.x;
                acc[i][1] += zf[i][kk] * w0.y;
                acc[i][2] += zf[i][kk] * w0.z;
                acc[i][3] += zf[i][kk] * w0.w;
                acc[i][4] += zf[i][kk] * w1.x;
                acc[i][5] += zf[i][kk] * w1.y;
                acc[i][6] += zf[i][kk] * w1.z;
                acc[i][7] += zf[i][kk] * w1.w;
            }
        }
    }
}

__global__ __launch_bounds__(512) void k_scores(const float* __restrict__ h_all,
                                                const float* __restrict__ z,
                                                const float* __restrict__ P,
                                                const float* __restrict__ Q,
                                                const float* __restrict__ Gm,
                                                const float* __restrict__ cv,
                                                const float* __restrict__ b_prior,
                                                const float* __restrict__ b_gen,
                                                float* __restrict__ part) {
    extern __shared__ unsigned short sm[];
    unsigned short* hT = sm;             // 64 x 512 bf16
    unsigned short* fz = sm + 64 * 512;  // 64 x [z(256) | z^2(256)] bf16
    int tid = threadIdx.x;
    int bt0 = blockIdx.x * 64;
    int vbase = blockIdx.y * 2560;
    for (int i = tid; i < 8192; i += 512) {
        int r = i >> 7, c4 = i & 127;
        float4 v = *(const float4*)(h_all + (size_t)(bt0 + r) * 512 + (c4 << 2));
        *(ushort4*)(hT + r * 512 + (c4 << 2)) =
            make_ushort4(f2bf(v.x), f2bf(v.y), f2bf(v.z), f2bf(v.w));
    }
    for (int i = tid; i < 4096; i += 512) {
        int r = i >> 6, c4 = i & 63;
        float4 v = *(const float4*)(z + (size_t)(bt0 + r) * 256 + (c4 << 2));
        *(ushort4*)(fz + r * 512 + (c4 << 2)) =
            make_ushort4(f2bf(v.x), f2bf(v.y), f2bf(v.z), f2bf(v.w));
        *(ushort4*)(fz + r * 512 + 256 + (c4 << 2)) =
            make_ushort4(f2bf(v.x * v.x), f2bf(v.y * v.y), f2bf(v.z * v.z), f2bf(v.w * v.w));
    }
    __syncthreads();
    int w = tid >> 6, vl = tid & 63;
    const unsigned short* Fh = hT + (w * 8) * 512;
    const unsigned short* Fz = fz + (w * 8) * 512;
    float m1[8], s1[8], m2[8], s2[8], m3[8], s3[8];
#pragma unroll
    for (int i = 0; i < 8; i++) {
        m1[i] = m2[i] = m3[i] = -1e30f;
        s1[i] = s2[i] = s3[i] = 0.f;
    }
    for (int it = 0; it < 5; it++) {
        int v0 = vbase + it * 512 + vl * 8;
        float bp[8], bg[8], cvv[8];
#pragma unroll
        for (int j = 0; j < 8; j++) {
            int v = v0 + j;
            bool ok = v < VV;
            bp[j] = ok ? b_prior[v] : 0.f;
            bg[j] = ok ? b_gen[v] : 0.f;
            cvv[j] = ok ? cv[v] : 0.f;
        }
        // phase C: gen logits (K=256, z half of fz)
        {
            float acc[8][8] = {};
            dot8(Fz, Gm + v0, 64, acc);
            float u[8];
#pragma unroll
            for (int i = 0; i < 8; i++) {
#pragma unroll
                for (int j = 0; j < 8; j++)
                    u[j] = (v0 + j < VV) ? acc[i][j] + bg[j] : -1e30f;
                lse_upd8(m3[i], s3[i], u);
            }
        }
        // phase A: prior logits (K=512 on h)
        float accA[8][8] = {};
        dot8(Fh, P + v0, 128, accA);
        // phase B: lp body (K=512 on [z; z^2])
        float accB[8][8] = {};
        dot8(Fz, Q + v0, 128, accB);
        float u[8];
#pragma unroll
        for (int i = 0; i < 8; i++) {
#pragma unroll
            for (int j = 0; j < 8; j++)
                u[j] = (v0 + j < VV) ? accA[i][j] + bp[j] : -1e30f;
            lse_upd8(m1[i], s1[i], u);
#pragma unroll
            for (int j = 0; j < 8; j++)
                u[j] = (v0 + j < VV) ? u[j] + accB[i][j] + cvv[j] : -1e30f;
            lse_upd8(m2[i], s2[i], u);
        }
    }
#pragma unroll
    for (int off = 1; off < 64; off <<= 1) {
#pragma unroll
        for (int i = 0; i < 8; i++) {
            lse_red(m1[i], s1[i], off);
            lse_red(m2[i], s2[i], off);
            lse_red(m3[i], s3[i], off);
        }
    }
    if (vl == 0) {
        int base = blockIdx.y * 6;
#pragma unroll
        for (int i = 0; i < 8; i++) {
            int bt = bt0 + w * 8 + i;
            part[(base + 0) * 4096 + bt] = m1[i];
            part[(base + 1) * 4096 + bt] = s1[i];
            part[(base + 2) * 4096 + bt] = m2[i];
            part[(base + 3) * 4096 + bt] = s2[i];
            part[(base + 4) * 4096 + bt] = m3[i];
            part[(base + 5) * 4096 + bt] = s3[i];
        }
    }
}

// ---------------- 7) gx = z . w_gen[x] + b_gen[x] ----------------
__global__ void k_gx(const float* __restrict__ z, const int* __restrict__ x,
                     const float* __restrict__ w_gen, const float* __restrict__ b_gen,
                     float* __restrict__ gx) {
    int bt = blockIdx.x, k = threadIdx.x;
    int xi = x[bt];
    float p = z[bt * 256 + k] * w_gen[xi * 256 + k];
    __shared__ float red[256];
    red[k] = p;
    __syncthreads();
    for (int s = 128; s > 0; s >>= 1) {
        if (k < s) red[k] += red[k + s];
        __syncthreads();
    }
    if (k == 0) gx[bt] = red[0] + b_gen[xi];
}

// ---------------- 8) finalize (merge 4 V-split partials) ----------------
__device__ __forceinline__ float lse4(const float* __restrict__ part, int comp, int bt) {
    float M = -1e30f, S = 0.f;
#pragma unroll
    for (int vs = 0; vs < 4; vs++) {
        float m = part[(vs * 6 + comp) * 4096 + bt];
        float s = part[(vs * 6 + comp + 1) * 4096 + bt];
        float Mn = fmaxf(M, m);
        S = S * __expf(M - Mn) + s * __expf(m - Mn);
        M = Mn;
    }
    return M + logf(S);
}

__global__ void k_final(const float* __restrict__ part, const float* __restrict__ qz,
                        const float* __restrict__ gxv, const int* __restrict__ x_sl,
                        float* __restrict__ out) {
    int tid = threadIdx.x;
    float S = 0.f;
    for (int bt = tid; bt < 4096; bt += 256) {
        int b = bt >> 7, t = bt & 127;
        if (t < x_sl[b]) {
            float lse1 = lse4(part, 0, bt);
            float lse2 = lse4(part, 2, bt);
            float lse3 = lse4(part, 4, bt);
            float p_z = lse2 - lse1;
            float kl = qz[bt] - p_z;
            float px = gxv[bt] - lse3;
            S += px - kl;
        }
    }
    __shared__ float red[256];
    red[tid] = S;
    __syncthreads();
    for (int s = 128; s > 0; s >>= 1) {
        if (tid < s) red[tid] += red[tid + s];
        __syncthreads();
    }
    if (tid == 0) {
        int sl = 0;
        for (int b = 0; b < 32; b++) sl += x_sl[b];
        out[0] = -(red[0] / (float)sl);
    }
}

extern "C" void kernel_launch(void* const* d_in, const int* in_sizes, int n_in,
                              void* d_out, int out_size, void* d_ws, size_t ws_size,
                              hipStream_t stream) {
    const int* x = (const int*)d_in[0];
    const int* x_sl = (const int*)d_in[1];
    const float* eps = (const float*)d_in[2];
    const float* emb = (const float*)d_in[3];
    const float* w_ih = (const float*)d_in[4];
    const float* w_hh = (const float*)d_in[5];
    const float* b_ih = (const float*)d_in[6];
    const float* b_hh = (const float*)d_in[7];
    const float* w_prior = (const float*)d_in[8];
    const float* b_prior = (const float*)d_in[9];
    const float* w_gen = (const float*)d_in[10];
    const float* b_gen = (const float*)d_in[11];

    float* ws = (float*)d_ws;
    float* z = ws;
    float* qz = ws + 1048576;
    float* h_all = ws + 1052672;
    float* gx = ws + 3149824;
    float* part = ws + 3153920;
    float* region = ws + 3252224;
    float* xp = region;
    uint4* wpIF = (uint4*)(region + 8388608);
    uint4* wpGO = wpIF + 65536;
    int* flags = (int*)(region + 13107200);
    float* P = region;
    float* Q = region + 5242880;
    float* G = region + 10485760;
    float* cv = region + 13107200;

    k_embed<<<4096, 256, 0, stream>>>(x, x_sl, eps, emb, z, qz);
    k_xp<<<dim3(32, 64), 256, 0, stream>>>(z, w_ih, b_ih, b_hh, xp);
    k_wpack2<<<dim3(256, 2), 256, 0, stream>>>(w_hh, wpIF, wpGO);
    hipMemsetAsync(flags, 0, 256 * sizeof(int), stream);
    {
        hipFuncSetAttribute((const void*)k_lstm, hipFuncAttributeMaxDynamicSharedMemorySize, 136192);
        void* args[] = {(void*)&xp, (void*)&wpIF, (void*)&wpGO, (void*)&h_all, (void*)&flags};
        hipLaunchCooperativeKernel((const void*)k_lstm, dim3(256), dim3(256), args, 136192, stream);
    }
    // xp/wpIF/wpGO/flags dead; overlay P/Q/G/cv
    k_cv<<<10000, 256, 0, stream>>>(emb, cv);
    k_qt<<<dim3(313, 8), dim3(32, 8), 0, stream>>>(emb, Q);
    k_transpose<<<dim3(313, 16), dim3(32, 8), 0, stream>>>(w_prior, P, 512);
    k_transpose<<<dim3(313, 8), dim3(32, 8), 0, stream>>>(w_gen, G, 256);
    hipFuncSetAttribute((const void*)k_scores, hipFuncAttributeMaxDynamicSharedMemorySize, 131072);
    k_scores<<<dim3(64, 4), 512, 131072, stream>>>(h_all, z, P, Q, G, cv, b_prior, b_gen, part);
    k_gx<<<4096, 256, 0, stream>>>(z, x, w_gen, b_gen, gx);
    k_final<<<1, 256, 0, stream>>>(part, qz, gx, x_sl, (float*)d_out);
}

// Round 7
// 1310.928 us; speedup vs baseline: 8.8794x; 1.8333x over previous
//
#include <hip/hip_runtime.h>
#include <hip/hip_bf16.h>
#include <math.h>

// Sizes fixed by the problem
#define BB 32
#define TT 128
#define KK 256
#define HH 512
#define VV 10000
#define VP 10240
#define BT 4096           // B*T
#define HLOG2PI 0.91893853320467274178f

// ---- workspace layout (float offsets) ----
// z       : 0          1048576   (BT*K)
// qz      : 1048576    4096
// h_all   : 1052672    2097152   (BT*H)
// gx      : 3149824    4096
// part    : 3153920    98304     (4 vs * 6 * 4096)
// region  : 3252224    13117440
//   xp    = region + 0        (8388608 = BT*4H)   [dead after k_lstm]
//   wpIF  = region + 8388608  (262144 floats = 1 MB f16)  [alive k_wpack2..k_lstm]
//   wpGO  = region + 8650752  (262144 floats = 1 MB f16)
//   flags = region + 13107200 (256 ints; dead after k_lstm, overwritten by cv)
//   After k_lstm (overlaying dead xp):
//   Pb = region + 0        (10240*512 bf16 = 2621440 floats)
//   Qb = region + 2621440  (10240*512 bf16)
//   Gb = region + 5242880  (10240*256 bf16 = 1310720 floats)
//   cv = region + 13107200 (10240)
// total 16,369,664 floats = 65.5 MB

typedef short bf16x8 __attribute__((ext_vector_type(8)));
typedef float f32x4 __attribute__((ext_vector_type(4)));

__device__ __forceinline__ float softplus_b(float x) {
    float ax = fabsf(x);
    return fmaxf(x, 0.0f) + log2f(1.0f + exp2f(-ax));
}
__device__ __forceinline__ float sigm(float x) { return 1.0f / (1.0f + expf(-x)); }
__device__ __forceinline__ unsigned short f2bf(float f) {
    unsigned u = __float_as_uint(f);
    u += 0x7FFFu + ((u >> 16) & 1u);
    return (unsigned short)(u >> 16);
}
typedef _Float16 h2f16 __attribute__((ext_vector_type(2)));
__device__ __forceinline__ unsigned pkh2(float a, float b) {
    h2f16 h;
    h.x = (_Float16)a;
    h.y = (_Float16)b;
    return *(unsigned*)&h;
}
__device__ __forceinline__ float fdot2u(unsigned a, unsigned b, float c) {
    h2f16 ah = *(h2f16*)&a, bh = *(h2f16*)&b;
#if __has_builtin(__builtin_amdgcn_fdot2)
    return __builtin_amdgcn_fdot2(ah, bh, c, false);
#else
    return c + (float)ah.x * (float)bh.x + (float)ah.y * (float)bh.y;
#endif
}

// ---------------- 1) embedding -> z, q_z_lp ----------------
__global__ void k_embed(const int* __restrict__ x, const int* __restrict__ x_sl,
                        const float* __restrict__ eps, const float* __restrict__ emb,
                        float* __restrict__ z, float* __restrict__ qz) {
    int bt = blockIdx.x;
    int b = bt >> 7, t = bt & 127;
    int k = threadIdx.x;
    int xi = x[bt];
    float e1 = emb[xi * 512 + k];
    float sg = softplus_b(emb[xi * 512 + 256 + k]);
    float ep = eps[bt * 256 + k];
    float mk = (t < x_sl[b]) ? 1.f : 0.f;
    z[bt * 256 + k] = (e1 + sg * ep) * mk;
    float q = -HLOG2PI - logf(sg) - 0.5f * ep * ep;
    __shared__ float red[256];
    red[k] = q;
    __syncthreads();
    for (int s = 128; s > 0; s >>= 1) {
        if (k < s) red[k] += red[k + s];
        __syncthreads();
    }
    if (k == 0) qz[bt] = red[0];
}

// ---------------- 2) x_proj = z_shift @ w_ih^T + b_ih + b_hh ----------------
__global__ __launch_bounds__(256) void k_xp(const float* __restrict__ z,
                                            const float* __restrict__ w_ih,
                                            const float* __restrict__ b_ih,
                                            const float* __restrict__ b_hh,
                                            float* __restrict__ xp) {
    __shared__ float At[64][68];
    __shared__ float Wt[64][68];
    int n0 = blockIdx.x * 64, m0 = blockIdx.y * 64;
    int tid = threadIdx.x;
    int tn = tid & 15, tm = tid >> 4;
    float acc[4][4] = {};
    for (int kc = 0; kc < 256; kc += 64) {
        __syncthreads();
        for (int i = tid; i < 1024; i += 256) {
            int r = i >> 4, c4 = i & 15;
            int bt = m0 + r;
            int t = bt & 127;
            float4 v = make_float4(0.f, 0.f, 0.f, 0.f);
            if (t > 0) v = *(const float4*)(z + (bt - 1) * 256 + kc + c4 * 4);
            *(float4*)&At[r][c4 * 4] = v;
        }
        for (int i = tid; i < 1024; i += 256) {
            int r = i >> 4, c4 = i & 15;
            float4 v = *(const float4*)(w_ih + (n0 + r) * 256 + kc + c4 * 4);
            *(float4*)&Wt[r][c4 * 4] = v;
        }
        __syncthreads();
        for (int kk = 0; kk < 16; kk++) {
            float4 a[4], w[4];
#pragma unroll
            for (int i = 0; i < 4; i++) a[i] = *(const float4*)&At[tm + 16 * i][kk * 4];
#pragma unroll
            for (int j = 0; j < 4; j++) w[j] = *(const float4*)&Wt[tn + 16 * j][kk * 4];
#pragma unroll
            for (int i = 0; i < 4; i++)
#pragma unroll
                for (int j = 0; j < 4; j++)
                    acc[i][j] += a[i].x * w[j].x + a[i].y * w[j].y + a[i].z * w[j].z + a[i].w * w[j].w;
        }
    }
#pragma unroll
    for (int i = 0; i < 4; i++) {
        int m = m0 + tm + 16 * i;
#pragma unroll
        for (int j = 0; j < 4; j++) {
            int n = n0 + tn + 16 * j;
            xp[m * 2048 + n] = acc[i][j] + b_ih[n] + b_hh[n];
        }
    }
}

// ---------------- 2b) pack w_hh -> f16 pairs for the j-partitioned LSTM ----------------
__global__ __launch_bounds__(256) void k_wpack2(const float* __restrict__ w_hh,
                                                uint4* __restrict__ wpIF,
                                                uint4* __restrict__ wpGO) {
    int o = blockIdx.x * 256 + threadIdx.x;  // 0..65535
    if (blockIdx.y == 0) {
        int j = o & 63, k4 = (o >> 6) & 127, m = o >> 13;
        const float* wi = w_hh + (size_t)((m << 6) + j) * 512 + (k4 << 2);
        const float* wf = w_hh + (size_t)(512 + (m << 6) + j) * 512 + (k4 << 2);
        uint4 u;
        u.x = pkh2(wi[0], wi[1]); u.y = pkh2(wi[2], wi[3]);
        u.z = pkh2(wf[0], wf[1]); u.w = pkh2(wf[2], wf[3]);
        wpIF[o] = u;
    } else {
        int j = o & 63, q = (o >> 6) & 31, kh = (o >> 11) & 3, m = o >> 13;
        int k4 = (kh << 5) + q;
        const float* wg = w_hh + (size_t)(1024 + (m << 6) + j) * 512 + (k4 << 2);
        const float* wo = w_hh + (size_t)(1536 + (m << 6) + j) * 512 + (k4 << 2);
        uint4 u;
        u.x = pkh2(wg[0], wg[1]); u.y = pkh2(wg[2], wg[3]);
        u.z = pkh2(wo[0], wo[1]); u.w = pkh2(wo[2], wo[3]);
        wpGO[o] = u;
    }
}

// ---------------- 3) LSTM: 8 j-slice blocks per batch element ----------------
__global__ __launch_bounds__(256, 1) void k_lstm(const float* __restrict__ xp,
                                                 const uint4* __restrict__ wpIF,
                                                 const uint4* __restrict__ wpGO,
                                                 float* __restrict__ h_all,
                                                 int* __restrict__ flag) {
    extern __shared__ char smc[];
    uint4* wif = (uint4*)smc;                   // [k4 128][j 64] = 128 KB
    unsigned* hs2 = (unsigned*)(smc + 131072);  // 256 f16-pairs of h_prev
    float* red = (float*)(smc + 132096);        // [4 gates][4 kh][64 j]
    int bid = blockIdx.x;
    int b = bid & 31;
    int m = bid >> 5;
    int tid = threadIdx.x;
    int j = tid & 63, kh = tid >> 6;
    const uint4* srcIF = wpIF + ((size_t)m << 13);
    for (int i = tid; i < 8192; i += 256) wif[i] = srcIF[i];
    uint4 wgo[32];
    const uint4* srcGO = wpGO + ((((size_t)m << 2) + kh) << 11) + j;
#pragma unroll
    for (int q = 0; q < 32; q++) wgo[q] = srcGO[q << 6];
    float c = 0.f;
    int* hall_i = (int*)h_all;
    __syncthreads();
    for (int t = 0; t < 128; t++) {
        float a0 = 0.f, a1 = 0.f, a2 = 0.f, a3 = 0.f;
        if (t > 0) {
            if (tid < 8) {
                while (__hip_atomic_load(&flag[(b << 3) + tid], __ATOMIC_RELAXED,
                                         __HIP_MEMORY_SCOPE_AGENT) < t) {}
            }
            __syncthreads();
            {
                const int* hp = hall_i + (size_t)((b << 7) + t - 1) * 512 + (tid << 1);
                int u0 = __hip_atomic_load(hp, __ATOMIC_RELAXED, __HIP_MEMORY_SCOPE_AGENT);
                int u1 = __hip_atomic_load(hp + 1, __ATOMIC_RELAXED, __HIP_MEMORY_SCOPE_AGENT);
                hs2[tid] = pkh2(__int_as_float(u0), __int_as_float(u1));
            }
            __syncthreads();
            const uint4* wl = wif + ((kh << 5) << 6) + j;
            const unsigned* hp2 = hs2 + (kh << 6);
#pragma unroll
            for (int q = 0; q < 32; q++) {
                uint4 A = wl[q << 6];
                uint4 B = wgo[q];
                unsigned p0 = hp2[(q << 1)];
                unsigned p1 = hp2[(q << 1) + 1];
                a0 = fdot2u(A.x, p0, a0); a0 = fdot2u(A.y, p1, a0);
                a1 = fdot2u(A.z, p0, a1); a1 = fdot2u(A.w, p1, a1);
                a2 = fdot2u(B.x, p0, a2); a2 = fdot2u(B.y, p1, a2);
                a3 = fdot2u(B.z, p0, a3); a3 = fdot2u(B.w, p1, a3);
            }
        }
        red[(0 * 4 + kh) * 64 + j] = a0;
        red[(1 * 4 + kh) * 64 + j] = a1;
        red[(2 * 4 + kh) * 64 + j] = a2;
        red[(3 * 4 + kh) * 64 + j] = a3;
        __syncthreads();
        if (tid < 64) {
            int jg = (m << 6) + tid;
            const float* xpr = xp + (size_t)((b << 7) + t) * 2048 + jg;
            float g0 = xpr[0], g1 = xpr[512], g2 = xpr[1024], g3 = xpr[1536];
#pragma unroll
            for (int q = 0; q < 4; q++) {
                g0 += red[(0 * 4 + q) * 64 + tid];
                g1 += red[(1 * 4 + q) * 64 + tid];
                g2 += red[(2 * 4 + q) * 64 + tid];
                g3 += red[(3 * 4 + q) * 64 + tid];
            }
            c = sigm(g1) * c + sigm(g0) * tanhf(g2);
            float h = sigm(g3) * tanhf(c);
            __hip_atomic_store(hall_i + (size_t)((b << 7) + t) * 512 + jg, __float_as_int(h),
                               __ATOMIC_RELAXED, __HIP_MEMORY_SCOPE_AGENT);
            if (tid == 0)
                __hip_atomic_store(&flag[(b << 3) + m], t + 1, __ATOMIC_RELEASE,
                                   __HIP_MEMORY_SCOPE_AGENT);
        }
        __syncthreads();
    }
}

// ---------------- 4a) cast weights -> bf16 row-major [v][K], pad rows zeroed ----------------
__global__ __launch_bounds__(256) void k_pack_w(const float* __restrict__ src,
                                                ushort* __restrict__ dst, int kshift) {
    int o = blockIdx.x * 256 + threadIdx.x;  // one ushort4 unit
    int c = o & ((1 << kshift) - 1);
    int r = o >> kshift;
    ushort4 u = make_ushort4(0, 0, 0, 0);
    if (r < VV) {
        float4 v = *(const float4*)(src + ((size_t)r << (kshift + 2)) + (c << 2));
        u = make_ushort4(f2bf(v.x), f2bf(v.y), f2bf(v.z), f2bf(v.w));
    }
    *(ushort4*)(dst + ((size_t)o << 2)) = u;
}

// ---------------- 4b) Qb rows [2*iv*mu (256) | -iv (256)] bf16 + const_v ----------------
__global__ void k_pack_q(const float* __restrict__ emb, ushort* __restrict__ Qb,
                         float* __restrict__ cv) {
    int v = blockIdx.x, k = threadIdx.x;
    if (v >= VV) {
        Qb[((size_t)v << 9) + k] = 0;
        Qb[((size_t)v << 9) + 256 + k] = 0;
        if (k == 0) cv[v] = 0.f;
        return;
    }
    float mu = emb[(size_t)v * 512 + k];
    float sg = softplus_b(emb[(size_t)v * 512 + 256 + k]);
    float iv = 0.5f / (sg * sg);
    Qb[((size_t)v << 9) + k] = f2bf(2.f * iv * mu);
    Qb[((size_t)v << 9) + 256 + k] = f2bf(-iv);
    float ct = -HLOG2PI - logf(sg) - mu * mu * iv;
    __shared__ float red[256];
    red[k] = ct;
    __syncthreads();
    for (int s = 128; s > 0; s >>= 1) {
        if (k < s) red[k] += red[k + s];
        __syncthreads();
    }
    if (k == 0) cv[v] = red[0];
}

// ---------------- 6) fused scores: MFMA GEMM + online LSE ----------------
// Block = 512 thr (8 waves = mh{0,1} x nq{0..3}), M-tile 64 bt rows staged once
// in LDS (fragment-linear [kc][m][32k] bf16). Wave = 32m x 64n slice; after the
// nt loop the 4 nq slices are LSE-merged through LDS (the round-6 bug was
// skipping this merge: 4 waves overwrote the same part[] -> loss off by log 4).
__global__ __launch_bounds__(512, 2) void k_scores(
    const float* __restrict__ h_all, const float* __restrict__ z,
    const ushort* __restrict__ Pb, const ushort* __restrict__ Qb,
    const ushort* __restrict__ Gb, const float* __restrict__ cv,
    const float* __restrict__ b_prior, const float* __restrict__ b_gen,
    float* __restrict__ part) {
    extern __shared__ ushort sm[];
    ushort* hT = sm;           // [kc 16][m 64][kk 32] = 64 KB
    ushort* fzT = sm + 32768;  // kc<8: z, kc>=8: z^2
    int tid = threadIdx.x;
    int vs = blockIdx.x & 3;
    int mb = blockIdx.x >> 2;
    int bt0 = mb << 6;
    int vbase = vs * 2560;
    for (int i = tid; i < 8192; i += 512) {
        int r = i >> 7, k4 = (i & 127) << 2;
        float4 v = *(const float4*)(h_all + (size_t)(bt0 + r) * 512 + k4);
        *(ushort4*)(hT + (k4 >> 5) * 2048 + r * 32 + (k4 & 31)) =
            make_ushort4(f2bf(v.x), f2bf(v.y), f2bf(v.z), f2bf(v.w));
    }
    for (int i = tid; i < 4096; i += 512) {
        int r = i >> 6, k4 = (i & 63) << 2;
        float4 v = *(const float4*)(z + (size_t)(bt0 + r) * 256 + k4);
        *(ushort4*)(fzT + (k4 >> 5) * 2048 + r * 32 + (k4 & 31)) =
            make_ushort4(f2bf(v.x), f2bf(v.y), f2bf(v.z), f2bf(v.w));
        *(ushort4*)(fzT + ((k4 >> 5) + 8) * 2048 + r * 32 + (k4 & 31)) =
            make_ushort4(f2bf(v.x * v.x), f2bf(v.y * v.y), f2bf(v.z * v.z), f2bf(v.w * v.w));
    }
    __syncthreads();
    int w = tid >> 6, l = tid & 63;
    int quad = l >> 4, ln = l & 15;
    int mh = w & 1, nq = w >> 1;  // wave: rows mh*32..+32, cols nq*64..+64
    const bf16x8* hT8 = (const bf16x8*)hT;
    const bf16x8* fz8 = (const bf16x8*)fzT;
    const bf16x8* Pb8 = (const bf16x8*)Pb;
    const bf16x8* Qb8 = (const bf16x8*)Qb;
    const bf16x8* Gb8 = (const bf16x8*)Gb;
    int aB0 = (((mh << 5) + ln) << 2) + quad;
    int aB1 = (((mh << 5) + 16 + ln) << 2) + quad;
    float Lm[3][8], Ls[3][8];
#pragma unroll
    for (int c = 0; c < 3; c++)
#pragma unroll
        for (int r = 0; r < 8; r++) { Lm[c][r] = -1e30f; Ls[c][r] = 0.f; }
    for (int nt = 0; nt < 10; nt++) {
        int n0 = vbase + nt * 256 + (nq << 6);
        f32x4 accA[2][4], accB[2][4], accC[2][4];
#pragma unroll
        for (int ms = 0; ms < 2; ms++)
#pragma unroll
            for (int ns = 0; ns < 4; ns++) {
                accA[ms][ns] = 0.f; accB[ms][ns] = 0.f; accC[ms][ns] = 0.f;
            }
        // chain A: prior logits, h (K=512) vs Pb
#pragma unroll 2
        for (int kc = 0; kc < 16; kc++) {
            bf16x8 a0 = hT8[kc * 256 + aB0];
            bf16x8 a1 = hT8[kc * 256 + aB1];
#pragma unroll
            for (int ns = 0; ns < 4; ns++) {
                bf16x8 b = Pb8[(size_t)(n0 + (ns << 4) + ln) * 64 + (kc << 2) + quad];
                accA[0][ns] = __builtin_amdgcn_mfma_f32_16x16x32_bf16(a0, b, accA[0][ns], 0, 0, 0);
                accA[1][ns] = __builtin_amdgcn_mfma_f32_16x16x32_bf16(a1, b, accA[1][ns], 0, 0, 0);
            }
        }
        // chains B+C on z (kc 0..7): Qb k<256 and Gb
#pragma unroll 2
        for (int kc = 0; kc < 8; kc++) {
            bf16x8 a0 = fz8[kc * 256 + aB0];
            bf16x8 a1 = fz8[kc * 256 + aB1];
#pragma unroll
            for (int ns = 0; ns < 4; ns++) {
                int row = n0 + (ns << 4) + ln;
                bf16x8 bq = Qb8[(size_t)row * 64 + (kc << 2) + quad];
                bf16x8 bg = Gb8[(size_t)row * 32 + (kc << 2) + quad];
                accB[0][ns] = __builtin_amdgcn_mfma_f32_16x16x32_bf16(a0, bq, accB[0][ns], 0, 0, 0);
                accB[1][ns] = __builtin_amdgcn_mfma_f32_16x16x32_bf16(a1, bq, accB[1][ns], 0, 0, 0);
                accC[0][ns] = __builtin_amdgcn_mfma_f32_16x16x32_bf16(a0, bg, accC[0][ns], 0, 0, 0);
                accC[1][ns] = __builtin_amdgcn_mfma_f32_16x16x32_bf16(a1, bg, accC[1][ns], 0, 0, 0);
            }
        }
        // chain B on z^2 (kc 8..15): Qb k>=256
#pragma unroll 2
        for (int kc = 8; kc < 16; kc++) {
            bf16x8 a0 = fz8[kc * 256 + aB0];
            bf16x8 a1 = fz8[kc * 256 + aB1];
#pragma unroll
            for (int ns = 0; ns < 4; ns++) {
                bf16x8 bq = Qb8[(size_t)(n0 + (ns << 4) + ln) * 64 + (kc << 2) + quad];
                accB[0][ns] = __builtin_amdgcn_mfma_f32_16x16x32_bf16(a0, bq, accB[0][ns], 0, 0, 0);
                accB[1][ns] = __builtin_amdgcn_mfma_f32_16x16x32_bf16(a1, bq, accB[1][ns], 0, 0, 0);
            }
        }
        // epilogue: online LSE per bt-row; C/D layout col=lane&15, row=quad*4+reg
#pragma unroll
        for (int ns = 0; ns < 4; ns++) {
            int col = n0 + (ns << 4) + ln;
            bool ok = col < VV;
            float bpv = ok ? b_prior[col] : 0.f;
            float bgv = ok ? b_gen[col] : 0.f;
            float cvv = ok ? cv[col] : 0.f;
#pragma unroll
            for (int ms = 0; ms < 2; ms++)
#pragma unroll
                for (int r = 0; r < 4; r++) {
                    int r8 = (ms << 2) + r;
                    float u1 = ok ? accA[ms][ns][r] + bpv : -1e30f;
                    float u2 = ok ? u1 + accB[ms][ns][r] + cvv : -1e30f;
                    float u3 = ok ? accC[ms][ns][r] + bgv : -1e30f;
                    float nm;
                    nm = fmaxf(Lm[0][r8], u1);
                    Ls[0][r8] = Ls[0][r8] * __expf(Lm[0][r8] - nm) + __expf(u1 - nm);
                    Lm[0][r8] = nm;
                    nm = fmaxf(Lm[1][r8], u2);
                    Ls[1][r8] = Ls[1][r8] * __expf(Lm[1][r8] - nm) + __expf(u2 - nm);
                    Lm[1][r8] = nm;
                    nm = fmaxf(Lm[2][r8], u3);
                    Ls[2][r8] = Ls[2][r8] * __expf(Lm[2][r8] - nm) + __expf(u3 - nm);
                    Lm[2][r8] = nm;
                }
        }
    }
    // merge across the 16 col-lanes (same rows)
#pragma unroll
    for (int off = 1; off <= 8; off <<= 1)
#pragma unroll
        for (int c = 0; c < 3; c++)
#pragma unroll
            for (int r8 = 0; r8 < 8; r8++) {
                float mo = __shfl_xor(Lm[c][r8], off);
                float so = __shfl_xor(Ls[c][r8], off);
                float nm = fmaxf(Lm[c][r8], mo);
                Ls[c][r8] = Ls[c][r8] * __expf(Lm[c][r8] - nm) + so * __expf(mo - nm);
                Lm[c][r8] = nm;
            }
    // block-level merge across the 4 nq column-slices (staging LDS is dead now)
    __syncthreads();
    float* bm = (float*)sm;   // [3][4 nq][64 rows]
    float* bs = bm + 768;     // [3][4 nq][64 rows]
    if (ln == 0) {
#pragma unroll
        for (int c = 0; c < 3; c++)
#pragma unroll
            for (int ms = 0; ms < 2; ms++)
#pragma unroll
                for (int r = 0; r < 4; r++) {
                    int row = (mh << 5) + (ms << 4) + (quad << 2) + r;
                    bm[(c * 4 + nq) * 64 + row] = Lm[c][(ms << 2) + r];
                    bs[(c * 4 + nq) * 64 + row] = Ls[c][(ms << 2) + r];
                }
    }
    __syncthreads();
    if (tid < 192) {
        int c = tid >> 6, row = tid & 63;
        float M = -1e30f, S = 0.f;
#pragma unroll
        for (int q = 0; q < 4; q++) {
            float m = bm[(c * 4 + q) * 64 + row];
            float s = bs[(c * 4 + q) * 64 + row];
            float Mn = fmaxf(M, m);
            S = S * __expf(M - Mn) + s * __expf(m - Mn);
            M = Mn;
        }
        part[(vs * 6 + c * 2) * 4096 + bt0 + row] = M;
        part[(vs * 6 + c * 2 + 1) * 4096 + bt0 + row] = S;
    }
}

// ---------------- 7) gx = z . w_gen[x] + b_gen[x] ----------------
__global__ void k_gx(const float* __restrict__ z, const int* __restrict__ x,
                     const float* __restrict__ w_gen, const float* __restrict__ b_gen,
                     float* __restrict__ gx) {
    int bt = blockIdx.x, k = threadIdx.x;
    int xi = x[bt];
    float p = z[bt * 256 + k] * w_gen[xi * 256 + k];
    __shared__ float red[256];
    red[k] = p;
    __syncthreads();
    for (int s = 128; s > 0; s >>= 1) {
        if (k < s) red[k] += red[k + s];
        __syncthreads();
    }
    if (k == 0) gx[bt] = red[0] + b_gen[xi];
}

// ---------------- 8) finalize (merge 4 V-split partials) ----------------
__device__ __forceinline__ float lse4(const float* __restrict__ part, int comp, int bt) {
    float M = -1e30f, S = 0.f;
#pragma unroll
    for (int vsi = 0; vsi < 4; vsi++) {
        float m = part[(vsi * 6 + comp) * 4096 + bt];
        float s = part[(vsi * 6 + comp + 1) * 4096 + bt];
        float Mn = fmaxf(M, m);
        S = S * __expf(M - Mn) + s * __expf(m - Mn);
        M = Mn;
    }
    return M + logf(S);
}

__global__ void k_final(const float* __restrict__ part, const float* __restrict__ qz,
                        const float* __restrict__ gxv, const int* __restrict__ x_sl,
                        float* __restrict__ out) {
    int tid = threadIdx.x;
    float S = 0.f;
    for (int bt = tid; bt < 4096; bt += 256) {
        int b = bt >> 7, t = bt & 127;
        if (t < x_sl[b]) {
            float lse1 = lse4(part, 0, bt);
            float lse2 = lse4(part, 2, bt);
            float lse3 = lse4(part, 4, bt);
            float p_z = lse2 - lse1;
            float kl = qz[bt] - p_z;
            float px = gxv[bt] - lse3;
            S += px - kl;
        }
    }
    __shared__ float red[256];
    red[tid] = S;
    __syncthreads();
    for (int s = 128; s > 0; s >>= 1) {
        if (tid < s) red[tid] += red[tid + s];
        __syncthreads();
    }
    if (tid == 0) {
        int sl = 0;
        for (int b = 0; b < 32; b++) sl += x_sl[b];
        out[0] = -(red[0] / (float)sl);
    }
}

extern "C" void kernel_launch(void* const* d_in, const int* in_sizes, int n_in,
                              void* d_out, int out_size, void* d_ws, size_t ws_size,
                              hipStream_t stream) {
    const int* x = (const int*)d_in[0];
    const int* x_sl = (const int*)d_in[1];
    const float* eps = (const float*)d_in[2];
    const float* emb = (const float*)d_in[3];
    const float* w_ih = (const float*)d_in[4];
    const float* w_hh = (const float*)d_in[5];
    const float* b_ih = (const float*)d_in[6];
    const float* b_hh = (const float*)d_in[7];
    const float* w_prior = (const float*)d_in[8];
    const float* b_prior = (const float*)d_in[9];
    const float* w_gen = (const float*)d_in[10];
    const float* b_gen = (const float*)d_in[11];

    float* ws = (float*)d_ws;
    float* z = ws;
    float* qz = ws + 1048576;
    float* h_all = ws + 1052672;
    float* gx = ws + 3149824;
    float* part = ws + 3153920;
    float* region = ws + 3252224;
    float* xp = region;
    uint4* wpIF = (uint4*)(region + 8388608);
    uint4* wpGO = wpIF + 65536;
    int* flags = (int*)(region + 13107200);
    ushort* Pb = (ushort*)(region);            // after lstm (xp dead)
    ushort* Qb = (ushort*)(region + 2621440);
    ushort* Gb = (ushort*)(region + 5242880);
    float* cv = region + 13107200;

    k_embed<<<4096, 256, 0, stream>>>(x, x_sl, eps, emb, z, qz);
    k_xp<<<dim3(32, 64), 256, 0, stream>>>(z, w_ih, b_ih, b_hh, xp);
    k_wpack2<<<dim3(256, 2), 256, 0, stream>>>(w_hh, wpIF, wpGO);
    hipMemsetAsync(flags, 0, 256 * sizeof(int), stream);
    {
        hipFuncSetAttribute((const void*)k_lstm, hipFuncAttributeMaxDynamicSharedMemorySize, 136192);
        void* args[] = {(void*)&xp, (void*)&wpIF, (void*)&wpGO, (void*)&h_all, (void*)&flags};
        hipLaunchCooperativeKernel((const void*)k_lstm, dim3(256), dim3(256), args, 136192, stream);
    }
    // xp/wpIF/wpGO/flags dead; overlay Pb/Qb/Gb/cv
    k_pack_w<<<5120, 256, 0, stream>>>(w_prior, Pb, 7);
    k_pack_w<<<2560, 256, 0, stream>>>(w_gen, Gb, 6);
    k_pack_q<<<10240, 256, 0, stream>>>(emb, Qb, cv);
    hipFuncSetAttribute((const void*)k_scores, hipFuncAttributeMaxDynamicSharedMemorySize, 131072);
    k_scores<<<256, 512, 131072, stream>>>(h_all, z, Pb, Qb, Gb, cv, b_prior, b_gen, part);
    k_gx<<<4096, 256, 0, stream>>>(z, x, w_gen, b_gen, gx);
    k_final<<<1, 256, 0, stream>>>(part, qz, gx, x_sl, (float*)d_out);
}

// Round 8
// 1045.679 us; speedup vs baseline: 11.1318x; 1.2537x over previous
//
#include <hip/hip_runtime.h>
#include <hip/hip_bf16.h>
#include <math.h>

// Sizes fixed by the problem
#define BB 32
#define TT 128
#define KK 256
#define HH 512
#define VV 10000
#define VP 10240
#define BT 4096           // B*T
#define HLOG2PI 0.91893853320467274178f

// ---- workspace layout (float offsets) ----
// z       : 0          1048576   (BT*K)
// qz      : 1048576    4096
// h_all   : 1052672    2097152   (BT*H)
// gx      : 3149824    4096
// region  : 3252224    13117440
//  phase 1 (lstm):
//   xp    = region + 0        (8388608 = BT*4H)
//   wpIF  = region + 8388608  (262144 floats f16-pairs)
//   wpGO  = region + 8650752  (262144)
//   hpk   = region + 8912896  (1048576 dwords = 4 MB, sentinel-sync h pairs)
//  phase 2 (scores), overlaying dead xp:
//   Pb   = region + 0        (10240*512 bf16)
//   Qb   = region + 2621440  (10240*512 bf16)
//   Gb   = region + 5242880  (10240*256 bf16)
//   part = region + 6553600  (8 vs * 6 * 4096 = 196608)
//   cv   = region + 13107200 (10240)
// total 16,369,664 floats = 65.5 MB

typedef short bf16x8 __attribute__((ext_vector_type(8)));
typedef float f32x4 __attribute__((ext_vector_type(4)));

__device__ __forceinline__ float softplus_b(float x) {
    float ax = fabsf(x);
    return fmaxf(x, 0.0f) + log2f(1.0f + exp2f(-ax));
}
__device__ __forceinline__ float sigm(float x) { return 1.0f / (1.0f + expf(-x)); }
__device__ __forceinline__ unsigned short f2bf(float f) {
    unsigned u = __float_as_uint(f);
    u += 0x7FFFu + ((u >> 16) & 1u);
    return (unsigned short)(u >> 16);
}
typedef _Float16 h2f16 __attribute__((ext_vector_type(2)));
__device__ __forceinline__ unsigned pkh2(float a, float b) {
    h2f16 h;
    h.x = (_Float16)a;
    h.y = (_Float16)b;
    return *(unsigned*)&h;
}
__device__ __forceinline__ float fdot2u(unsigned a, unsigned b, float c) {
    h2f16 ah = *(h2f16*)&a, bh = *(h2f16*)&b;
#if __has_builtin(__builtin_amdgcn_fdot2)
    return __builtin_amdgcn_fdot2(ah, bh, c, false);
#else
    return c + (float)ah.x * (float)bh.x + (float)ah.y * (float)bh.y;
#endif
}

// ---------------- 1) embedding -> z, q_z_lp ----------------
__global__ void k_embed(const int* __restrict__ x, const int* __restrict__ x_sl,
                        const float* __restrict__ eps, const float* __restrict__ emb,
                        float* __restrict__ z, float* __restrict__ qz) {
    int bt = blockIdx.x;
    int b = bt >> 7, t = bt & 127;
    int k = threadIdx.x;
    int xi = x[bt];
    float e1 = emb[xi * 512 + k];
    float sg = softplus_b(emb[xi * 512 + 256 + k]);
    float ep = eps[bt * 256 + k];
    float mk = (t < x_sl[b]) ? 1.f : 0.f;
    z[bt * 256 + k] = (e1 + sg * ep) * mk;
    float q = -HLOG2PI - logf(sg) - 0.5f * ep * ep;
    __shared__ float red[256];
    red[k] = q;
    __syncthreads();
    for (int s = 128; s > 0; s >>= 1) {
        if (k < s) red[k] += red[k + s];
        __syncthreads();
    }
    if (k == 0) qz[bt] = red[0];
}

// ---------------- 2) x_proj = z_shift @ w_ih^T + b_ih + b_hh ----------------
__global__ __launch_bounds__(256) void k_xp(const float* __restrict__ z,
                                            const float* __restrict__ w_ih,
                                            const float* __restrict__ b_ih,
                                            const float* __restrict__ b_hh,
                                            float* __restrict__ xp) {
    __shared__ float At[64][68];
    __shared__ float Wt[64][68];
    int n0 = blockIdx.x * 64, m0 = blockIdx.y * 64;
    int tid = threadIdx.x;
    int tn = tid & 15, tm = tid >> 4;
    float acc[4][4] = {};
    for (int kc = 0; kc < 256; kc += 64) {
        __syncthreads();
        for (int i = tid; i < 1024; i += 256) {
            int r = i >> 4, c4 = i & 15;
            int bt = m0 + r;
            int t = bt & 127;
            float4 v = make_float4(0.f, 0.f, 0.f, 0.f);
            if (t > 0) v = *(const float4*)(z + (bt - 1) * 256 + kc + c4 * 4);
            *(float4*)&At[r][c4 * 4] = v;
        }
        for (int i = tid; i < 1024; i += 256) {
            int r = i >> 4, c4 = i & 15;
            float4 v = *(const float4*)(w_ih + (n0 + r) * 256 + kc + c4 * 4);
            *(float4*)&Wt[r][c4 * 4] = v;
        }
        __syncthreads();
        for (int kk = 0; kk < 16; kk++) {
            float4 a[4], w[4];
#pragma unroll
            for (int i = 0; i < 4; i++) a[i] = *(const float4*)&At[tm + 16 * i][kk * 4];
#pragma unroll
            for (int j = 0; j < 4; j++) w[j] = *(const float4*)&Wt[tn + 16 * j][kk * 4];
#pragma unroll
            for (int i = 0; i < 4; i++)
#pragma unroll
                for (int j = 0; j < 4; j++)
                    acc[i][j] += a[i].x * w[j].x + a[i].y * w[j].y + a[i].z * w[j].z + a[i].w * w[j].w;
        }
    }
#pragma unroll
    for (int i = 0; i < 4; i++) {
        int m = m0 + tm + 16 * i;
#pragma unroll
        for (int j = 0; j < 4; j++) {
            int n = n0 + tn + 16 * j;
            xp[m * 2048 + n] = acc[i][j] + b_ih[n] + b_hh[n];
        }
    }
}

// ---------------- 2b) pack w_hh -> f16 pairs, layouts for k_lstm v2 ----------------
// wpIF idx = m*8192 + q*256 + j_local*4 + kq : uint4 = (i_k01,i_k23,f_k01,f_k23),
//   k = kq*128 + q*4. Wave-linear for LDS reads (lane = j_local*4+kq - 64w).
// wpGO idx = ((m*64+j_local)*4 + kq)*32 + q : per-thread contiguous 512 B stream.
__global__ __launch_bounds__(256) void k_wpack2(const float* __restrict__ w_hh,
                                                uint4* __restrict__ wpIF,
                                                uint4* __restrict__ wpGO) {
    int o = blockIdx.x * 256 + threadIdx.x;  // 0..65535
    if (blockIdx.y == 0) {
        int kq = o & 3, j_local = (o >> 2) & 63, q = (o >> 8) & 31, m = o >> 13;
        int jg = (m << 6) + j_local;
        int k = (kq << 7) + (q << 2);
        const float* wi = w_hh + (size_t)jg * 512 + k;
        const float* wf = w_hh + (size_t)(512 + jg) * 512 + k;
        uint4 u;
        u.x = pkh2(wi[0], wi[1]); u.y = pkh2(wi[2], wi[3]);
        u.z = pkh2(wf[0], wf[1]); u.w = pkh2(wf[2], wf[3]);
        wpIF[o] = u;
    } else {
        int q = o & 31, kq = (o >> 5) & 3, j_local = (o >> 7) & 63, m = o >> 13;
        int jg = (m << 6) + j_local;
        int k = (kq << 7) + (q << 2);
        const float* wg = w_hh + (size_t)(1024 + jg) * 512 + k;
        const float* wo = w_hh + (size_t)(1536 + jg) * 512 + k;
        uint4 u;
        u.x = pkh2(wg[0], wg[1]); u.y = pkh2(wg[2], wg[3]);
        u.z = pkh2(wo[0], wo[1]); u.w = pkh2(wo[2], wo[3]);
        wpGO[o] = u;
    }
}

// ---------------- 3) LSTM v2: flag-free sentinel sync, 1 barrier/step ----------------
// 256 blocks x 256 thr, cooperative. Block (m = bid>>5, b = bid&31): j-slice of 64.
// Wave w owns j_local [16w,16w+16); lane = (jj, kq): 4-gate partials over 128 k,
// reduced by shfl_xor(1,2). h exchange: producers store f16-pair dwords into
// hpk[b][t][256] (relaxed agent); consumers poll their OWN dword against the
// 0xFFFFFFFF sentinel (f16 NaN pair - unreachable for h in (-1,1)). Data = signal:
// one L3 RTT, no flags, no release. hs2 double-buffered -> single __syncthreads.
__global__ __launch_bounds__(256, 1) void k_lstm(const float* __restrict__ xp,
                                                 const uint4* __restrict__ wpIF,
                                                 const uint4* __restrict__ wpGO,
                                                 float* __restrict__ h_all,
                                                 unsigned* __restrict__ hpk) {
    extern __shared__ char smc[];
    uint4* wif = (uint4*)smc;                   // [q 32][wave-linear 256] = 128 KB
    unsigned* hs2 = (unsigned*)(smc + 131072);  // [2][256] dwords
    int bid = blockIdx.x;
    int b = bid & 31;
    int m = bid >> 5;
    int tid = threadIdx.x;
    int w = tid >> 6, l = tid & 63;
    int jj = l >> 2, kq = l & 3;
    int j_local = (w << 4) + jj;
    int j_global = (m << 6) + j_local;
    const uint4* srcIF = wpIF + ((size_t)m << 13);
    for (int i = tid; i < 8192; i += 256) wif[i] = srcIF[i];
    uint4 wgo[32];
    const uint4* srcGO = wpGO + ((size_t)((((m << 6) + j_local) << 2) + kq) << 5);
#pragma unroll
    for (int q = 0; q < 32; q++) wgo[q] = srcGO[q];
    const uint4* wifp = wif + (w << 6) + l;
    float c = 0.f;
    __syncthreads();
    for (int t = 0; t < 128; t++) {
        int bt = (b << 7) + t;
        float xg0 = 0.f, xg1 = 0.f, xg2 = 0.f, xg3 = 0.f;
        if (kq == 0) {  // prefetch xp before the poll (independent loads)
            const float* xpr = xp + (size_t)bt * 2048 + j_global;
            xg0 = xpr[0]; xg1 = xpr[512]; xg2 = xpr[1024]; xg3 = xpr[1536];
        }
        float a0 = 0.f, a1 = 0.f, a2 = 0.f, a3 = 0.f;
        if (t > 0) {
            const unsigned* src = hpk + ((size_t)(bt - 1) << 8);
            unsigned u;
            do {
                u = __hip_atomic_load(src + tid, __ATOMIC_RELAXED, __HIP_MEMORY_SCOPE_AGENT);
            } while (u == 0xFFFFFFFFu);
            unsigned* hbuf = hs2 + (((t - 1) & 1) << 8);
            hbuf[tid] = u;
            __syncthreads();
            const unsigned* hp2 = hbuf + (kq << 6);
#pragma unroll
            for (int q = 0; q < 32; q++) {
                uint4 A = wifp[q << 8];
                uint4 B = wgo[q];
                unsigned p0 = hp2[q << 1];
                unsigned p1 = hp2[(q << 1) + 1];
                a0 = fdot2u(A.x, p0, a0); a0 = fdot2u(A.y, p1, a0);
                a1 = fdot2u(A.z, p0, a1); a1 = fdot2u(A.w, p1, a1);
                a2 = fdot2u(B.x, p0, a2); a2 = fdot2u(B.y, p1, a2);
                a3 = fdot2u(B.z, p0, a3); a3 = fdot2u(B.w, p1, a3);
            }
#pragma unroll
            for (int off = 1; off <= 2; off <<= 1) {
                a0 += __shfl_xor(a0, off);
                a1 += __shfl_xor(a1, off);
                a2 += __shfl_xor(a2, off);
                a3 += __shfl_xor(a3, off);
            }
        }
        float h = 0.f;
        if (kq == 0) {
            float g0 = xg0 + a0, g1 = xg1 + a1, g2 = xg2 + a2, g3 = xg3 + a3;
            c = sigm(g1) * c + sigm(g0) * tanhf(g2);
            h = sigm(g3) * tanhf(c);
            h_all[(size_t)bt * 512 + j_global] = h;  // plain store, read post-kernel
        }
        float hp = __shfl_xor(h, 4);  // leader jj even <- h of jj+1
        if (kq == 0 && (jj & 1) == 0) {
            unsigned u = pkh2(h, hp);
            __hip_atomic_store(hpk + ((size_t)bt << 8) + (m << 5) + (w << 3) + (jj >> 1),
                               u, __ATOMIC_RELAXED, __HIP_MEMORY_SCOPE_AGENT);
        }
    }
}

// ---------------- 4a) cast weights -> bf16 row-major [v][K], pad rows zeroed ----------------
__global__ __launch_bounds__(256) void k_pack_w(const float* __restrict__ src,
                                                ushort* __restrict__ dst, int kshift) {
    int o = blockIdx.x * 256 + threadIdx.x;  // one ushort4 unit
    int c = o & ((1 << kshift) - 1);
    int r = o >> kshift;
    ushort4 u = make_ushort4(0, 0, 0, 0);
    if (r < VV) {
        float4 v = *(const float4*)(src + ((size_t)r << (kshift + 2)) + (c << 2));
        u = make_ushort4(f2bf(v.x), f2bf(v.y), f2bf(v.z), f2bf(v.w));
    }
    *(ushort4*)(dst + ((size_t)o << 2)) = u;
}

// ---------------- 4b) Qb rows [2*iv*mu (256) | -iv (256)] bf16 + const_v ----------------
__global__ void k_pack_q(const float* __restrict__ emb, ushort* __restrict__ Qb,
                         float* __restrict__ cv) {
    int v = blockIdx.x, k = threadIdx.x;
    if (v >= VV) {
        Qb[((size_t)v << 9) + k] = 0;
        Qb[((size_t)v << 9) + 256 + k] = 0;
        if (k == 0) cv[v] = 0.f;
        return;
    }
    float mu = emb[(size_t)v * 512 + k];
    float sg = softplus_b(emb[(size_t)v * 512 + 256 + k]);
    float iv = 0.5f / (sg * sg);
    Qb[((size_t)v << 9) + k] = f2bf(2.f * iv * mu);
    Qb[((size_t)v << 9) + 256 + k] = f2bf(-iv);
    float ct = -HLOG2PI - logf(sg) - mu * mu * iv;
    __shared__ float red[256];
    red[k] = ct;
    __syncthreads();
    for (int s = 128; s > 0; s >>= 1) {
        if (k < s) red[k] += red[k + s];
        __syncthreads();
    }
    if (k == 0) cv[v] = red[0];
}

// ---------------- 6) fused scores: MFMA GEMM + online LSE ----------------
// 512 blocks = 64 m-tiles x 8 v-splits; vs = blockIdx&7 == XCD (%8 round-robin
// heuristic) so each XCD's blocks stream ONE 3.3 MB weight slice that fits its
// 4 MB L2 (L3 traffic 1.66 GB -> ~26 MB). Correctness independent of mapping.
__global__ __launch_bounds__(512, 2) void k_scores(
    const float* __restrict__ h_all, const float* __restrict__ z,
    const ushort* __restrict__ Pb, const ushort* __restrict__ Qb,
    const ushort* __restrict__ Gb, const float* __restrict__ cv,
    const float* __restrict__ b_prior, const float* __restrict__ b_gen,
    float* __restrict__ part) {
    extern __shared__ ushort sm[];
    ushort* hT = sm;           // [kc 16][m 64][kk 32] = 64 KB
    ushort* fzT = sm + 32768;  // kc<8: z, kc>=8: z^2
    int tid = threadIdx.x;
    int vs = blockIdx.x & 7;
    int mb = blockIdx.x >> 3;
    int bt0 = mb << 6;
    int vbase = vs * 1280;
    for (int i = tid; i < 8192; i += 512) {
        int r = i >> 7, k4 = (i & 127) << 2;
        float4 v = *(const float4*)(h_all + (size_t)(bt0 + r) * 512 + k4);
        *(ushort4*)(hT + (k4 >> 5) * 2048 + r * 32 + (k4 & 31)) =
            make_ushort4(f2bf(v.x), f2bf(v.y), f2bf(v.z), f2bf(v.w));
    }
    for (int i = tid; i < 4096; i += 512) {
        int r = i >> 6, k4 = (i & 63) << 2;
        float4 v = *(const float4*)(z + (size_t)(bt0 + r) * 256 + k4);
        *(ushort4*)(fzT + (k4 >> 5) * 2048 + r * 32 + (k4 & 31)) =
            make_ushort4(f2bf(v.x), f2bf(v.y), f2bf(v.z), f2bf(v.w));
        *(ushort4*)(fzT + ((k4 >> 5) + 8) * 2048 + r * 32 + (k4 & 31)) =
            make_ushort4(f2bf(v.x * v.x), f2bf(v.y * v.y), f2bf(v.z * v.z), f2bf(v.w * v.w));
    }
    __syncthreads();
    int w = tid >> 6, l = tid & 63;
    int quad = l >> 4, ln = l & 15;
    int mh = w & 1, nq = w >> 1;  // wave: rows mh*32..+32, cols nq*64..+64
    const bf16x8* hT8 = (const bf16x8*)hT;
    const bf16x8* fz8 = (const bf16x8*)fzT;
    const bf16x8* Pb8 = (const bf16x8*)Pb;
    const bf16x8* Qb8 = (const bf16x8*)Qb;
    const bf16x8* Gb8 = (const bf16x8*)Gb;
    int aB0 = (((mh << 5) + ln) << 2) + quad;
    int aB1 = (((mh << 5) + 16 + ln) << 2) + quad;
    float Lm[3][8], Ls[3][8];
#pragma unroll
    for (int c = 0; c < 3; c++)
#pragma unroll
        for (int r = 0; r < 8; r++) { Lm[c][r] = -1e30f; Ls[c][r] = 0.f; }
    for (int nt = 0; nt < 5; nt++) {
        int n0 = vbase + nt * 256 + (nq << 6);
        f32x4 accA[2][4], accB[2][4], accC[2][4];
#pragma unroll
        for (int ms = 0; ms < 2; ms++)
#pragma unroll
            for (int ns = 0; ns < 4; ns++) {
                accA[ms][ns] = 0.f; accB[ms][ns] = 0.f; accC[ms][ns] = 0.f;
            }
        // chain A: prior logits, h (K=512) vs Pb
#pragma unroll 2
        for (int kc = 0; kc < 16; kc++) {
            bf16x8 a0 = hT8[kc * 256 + aB0];
            bf16x8 a1 = hT8[kc * 256 + aB1];
#pragma unroll
            for (int ns = 0; ns < 4; ns++) {
                bf16x8 b = Pb8[(size_t)(n0 + (ns << 4) + ln) * 64 + (kc << 2) + quad];
                accA[0][ns] = __builtin_amdgcn_mfma_f32_16x16x32_bf16(a0, b, accA[0][ns], 0, 0, 0);
                accA[1][ns] = __builtin_amdgcn_mfma_f32_16x16x32_bf16(a1, b, accA[1][ns], 0, 0, 0);
            }
        }
        // chains B+C on z (kc 0..7): Qb k<256 and Gb
#pragma unroll 2
        for (int kc = 0; kc < 8; kc++) {
            bf16x8 a0 = fz8[kc * 256 + aB0];
            bf16x8 a1 = fz8[kc * 256 + aB1];
#pragma unroll
            for (int ns = 0; ns < 4; ns++) {
                int row = n0 + (ns << 4) + ln;
                bf16x8 bq = Qb8[(size_t)row * 64 + (kc << 2) + quad];
                bf16x8 bg = Gb8[(size_t)row * 32 + (kc << 2) + quad];
                accB[0][ns] = __builtin_amdgcn_mfma_f32_16x16x32_bf16(a0, bq, accB[0][ns], 0, 0, 0);
                accB[1][ns] = __builtin_amdgcn_mfma_f32_16x16x32_bf16(a1, bq, accB[1][ns], 0, 0, 0);
                accC[0][ns] = __builtin_amdgcn_mfma_f32_16x16x32_bf16(a0, bg, accC[0][ns], 0, 0, 0);
                accC[1][ns] = __builtin_amdgcn_mfma_f32_16x16x32_bf16(a1, bg, accC[1][ns], 0, 0, 0);
            }
        }
        // chain B on z^2 (kc 8..15): Qb k>=256
#pragma unroll 2
        for (int kc = 8; kc < 16; kc++) {
            bf16x8 a0 = fz8[kc * 256 + aB0];
            bf16x8 a1 = fz8[kc * 256 + aB1];
#pragma unroll
            for (int ns = 0; ns < 4; ns++) {
                bf16x8 bq = Qb8[(size_t)(n0 + (ns << 4) + ln) * 64 + (kc << 2) + quad];
                accB[0][ns] = __builtin_amdgcn_mfma_f32_16x16x32_bf16(a0, bq, accB[0][ns], 0, 0, 0);
                accB[1][ns] = __builtin_amdgcn_mfma_f32_16x16x32_bf16(a1, bq, accB[1][ns], 0, 0, 0);
            }
        }
        // epilogue: online LSE per bt-row; C/D layout col=lane&15, row=quad*4+reg
#pragma unroll
        for (int ns = 0; ns < 4; ns++) {
            int col = n0 + (ns << 4) + ln;
            bool ok = col < VV;
            float bpv = ok ? b_prior[col] : 0.f;
            float bgv = ok ? b_gen[col] : 0.f;
            float cvv = ok ? cv[col] : 0.f;
#pragma unroll
            for (int ms = 0; ms < 2; ms++)
#pragma unroll
                for (int r = 0; r < 4; r++) {
                    int r8 = (ms << 2) + r;
                    float u1 = ok ? accA[ms][ns][r] + bpv : -1e30f;
                    float u2 = ok ? u1 + accB[ms][ns][r] + cvv : -1e30f;
                    float u3 = ok ? accC[ms][ns][r] + bgv : -1e30f;
                    float nm;
                    nm = fmaxf(Lm[0][r8], u1);
                    Ls[0][r8] = Ls[0][r8] * __expf(Lm[0][r8] - nm) + __expf(u1 - nm);
                    Lm[0][r8] = nm;
                    nm = fmaxf(Lm[1][r8], u2);
                    Ls[1][r8] = Ls[1][r8] * __expf(Lm[1][r8] - nm) + __expf(u2 - nm);
                    Lm[1][r8] = nm;
                    nm = fmaxf(Lm[2][r8], u3);
                    Ls[2][r8] = Ls[2][r8] * __expf(Lm[2][r8] - nm) + __expf(u3 - nm);
                    Lm[2][r8] = nm;
                }
        }
    }
    // merge across the 16 col-lanes (same rows)
#pragma unroll
    for (int off = 1; off <= 8; off <<= 1)
#pragma unroll
        for (int c = 0; c < 3; c++)
#pragma unroll
            for (int r8 = 0; r8 < 8; r8++) {
                float mo = __shfl_xor(Lm[c][r8], off);
                float so = __shfl_xor(Ls[c][r8], off);
                float nm = fmaxf(Lm[c][r8], mo);
                Ls[c][r8] = Ls[c][r8] * __expf(Lm[c][r8] - nm) + so * __expf(mo - nm);
                Lm[c][r8] = nm;
            }
    // block-level merge across the 4 nq column-slices (staging LDS is dead now)
    __syncthreads();
    float* bm = (float*)sm;   // [3][4 nq][64 rows]
    float* bs = bm + 768;     // [3][4 nq][64 rows]
    if (ln == 0) {
#pragma unroll
        for (int c = 0; c < 3; c++)
#pragma unroll
            for (int ms = 0; ms < 2; ms++)
#pragma unroll
                for (int r = 0; r < 4; r++) {
                    int row = (mh << 5) + (ms << 4) + (quad << 2) + r;
                    bm[(c * 4 + nq) * 64 + row] = Lm[c][(ms << 2) + r];
                    bs[(c * 4 + nq) * 64 + row] = Ls[c][(ms << 2) + r];
                }
    }
    __syncthreads();
    if (tid < 192) {
        int c = tid >> 6, row = tid & 63;
        float M = -1e30f, S = 0.f;
#pragma unroll
        for (int q = 0; q < 4; q++) {
            float m = bm[(c * 4 + q) * 64 + row];
            float s = bs[(c * 4 + q) * 64 + row];
            float Mn = fmaxf(M, m);
            S = S * __expf(M - Mn) + s * __expf(m - Mn);
            M = Mn;
        }
        part[(vs * 6 + c * 2) * 4096 + bt0 + row] = M;
        part[(vs * 6 + c * 2 + 1) * 4096 + bt0 + row] = S;
    }
}

// ---------------- 7) gx = z . w_gen[x] + b_gen[x] ----------------
__global__ void k_gx(const float* __restrict__ z, const int* __restrict__ x,
                     const float* __restrict__ w_gen, const float* __restrict__ b_gen,
                     float* __restrict__ gx) {
    int bt = blockIdx.x, k = threadIdx.x;
    int xi = x[bt];
    float p = z[bt * 256 + k] * w_gen[xi * 256 + k];
    __shared__ float red[256];
    red[k] = p;
    __syncthreads();
    for (int s = 128; s > 0; s >>= 1) {
        if (k < s) red[k] += red[k + s];
        __syncthreads();
    }
    if (k == 0) gx[bt] = red[0] + b_gen[xi];
}

// ---------------- 8) finalize (merge 8 V-split partials) ----------------
__device__ __forceinline__ float lse8(const float* __restrict__ part, int comp, int bt) {
    float M = -1e30f, S = 0.f;
#pragma unroll
    for (int vsi = 0; vsi < 8; vsi++) {
        float m = part[(vsi * 6 + comp) * 4096 + bt];
        float s = part[(vsi * 6 + comp + 1) * 4096 + bt];
        float Mn = fmaxf(M, m);
        S = S * __expf(M - Mn) + s * __expf(m - Mn);
        M = Mn;
    }
    return M + logf(S);
}

__global__ void k_final(const float* __restrict__ part, const float* __restrict__ qz,
                        const float* __restrict__ gxv, const int* __restrict__ x_sl,
                        float* __restrict__ out) {
    int tid = threadIdx.x;
    float S = 0.f;
    for (int bt = tid; bt < 4096; bt += 256) {
        int b = bt >> 7, t = bt & 127;
        if (t < x_sl[b]) {
            float lse1 = lse8(part, 0, bt);
            float lse2 = lse8(part, 2, bt);
            float lse3 = lse8(part, 4, bt);
            float p_z = lse2 - lse1;
            float kl = qz[bt] - p_z;
            float px = gxv[bt] - lse3;
            S += px - kl;
        }
    }
    __shared__ float red[256];
    red[tid] = S;
    __syncthreads();
    for (int s = 128; s > 0; s >>= 1) {
        if (tid < s) red[tid] += red[tid + s];
        __syncthreads();
    }
    if (tid == 0) {
        int sl = 0;
        for (int b = 0; b < 32; b++) sl += x_sl[b];
        out[0] = -(red[0] / (float)sl);
    }
}

extern "C" void kernel_launch(void* const* d_in, const int* in_sizes, int n_in,
                              void* d_out, int out_size, void* d_ws, size_t ws_size,
                              hipStream_t stream) {
    const int* x = (const int*)d_in[0];
    const int* x_sl = (const int*)d_in[1];
    const float* eps = (const float*)d_in[2];
    const float* emb = (const float*)d_in[3];
    const float* w_ih = (const float*)d_in[4];
    const float* w_hh = (const float*)d_in[5];
    const float* b_ih = (const float*)d_in[6];
    const float* b_hh = (const float*)d_in[7];
    const float* w_prior = (const float*)d_in[8];
    const float* b_prior = (const float*)d_in[9];
    const float* w_gen = (const float*)d_in[10];
    const float* b_gen = (const float*)d_in[11];

    float* ws = (float*)d_ws;
    float* z = ws;
    float* qz = ws + 1048576;
    float* h_all = ws + 1052672;
    float* gx = ws + 3149824;
    float* region = ws + 3252224;
    float* xp = region;
    uint4* wpIF = (uint4*)(region + 8388608);
    uint4* wpGO = wpIF + 65536;
    unsigned* hpk = (unsigned*)(region + 8912896);  // 1048576 dwords
    ushort* Pb = (ushort*)(region);                 // phase 2 (xp dead)
    ushort* Qb = (ushort*)(region + 2621440);
    ushort* Gb = (ushort*)(region + 5242880);
    float* part = region + 6553600;                 // 8*6*4096
    float* cv = region + 13107200;

    k_embed<<<4096, 256, 0, stream>>>(x, x_sl, eps, emb, z, qz);
    k_xp<<<dim3(32, 64), 256, 0, stream>>>(z, w_ih, b_ih, b_hh, xp);
    k_wpack2<<<dim3(256, 2), 256, 0, stream>>>(w_hh, wpIF, wpGO);
    hipMemsetAsync(hpk, 0xFF, 4194304, stream);  // sentinel: f16 NaN pairs
    {
        hipFuncSetAttribute((const void*)k_lstm, hipFuncAttributeMaxDynamicSharedMemorySize, 133120);
        void* args[] = {(void*)&xp, (void*)&wpIF, (void*)&wpGO, (void*)&h_all, (void*)&hpk};
        hipLaunchCooperativeKernel((const void*)k_lstm, dim3(256), dim3(256), args, 133120, stream);
    }
    // xp/wpIF/wpGO/hpk dead; overlay Pb/Qb/Gb/part/cv
    k_pack_w<<<5120, 256, 0, stream>>>(w_prior, Pb, 7);
    k_pack_w<<<2560, 256, 0, stream>>>(w_gen, Gb, 6);
    k_pack_q<<<10240, 256, 0, stream>>>(emb, Qb, cv);
    hipFuncSetAttribute((const void*)k_scores, hipFuncAttributeMaxDynamicSharedMemorySize, 131072);
    k_scores<<<512, 512, 131072, stream>>>(h_all, z, Pb, Qb, Gb, cv, b_prior, b_gen, part);
    k_gx<<<4096, 256, 0, stream>>>(z, x, w_gen, b_gen, gx);
    k_final<<<1, 256, 0, stream>>>(part, qz, gx, x_sl, (float*)d_out);
}